// Round 12
// baseline (688.557 us; speedup 1.0000x reference)
//
#include <hip/hip_runtime.h>

// Problem constants (from reference)
#define NN 38332          // nodes
#define FF 544            // input features
#define CC 128            // channels
#define LL 4              // gcn layers
#define EE (NN*16)        // edges (613312)
#define PP 38333          // POI_LEN (output size)

typedef __attribute__((ext_vector_type(8))) short short8v;
typedef __attribute__((ext_vector_type(4))) float floatx4;

static __device__ __forceinline__ float lrelu(float x) {
    return x >= 0.f ? x : 0.01f * x;
}

// fp32 -> bf16 round-to-nearest-even (bit trick)
static __device__ __forceinline__ short f2bf(float f) {
    unsigned u = __float_as_uint(f);
    unsigned r = (u + 0x7fffu + ((u >> 16) & 1u)) >> 16;
    return (short)r;
}
static __device__ __forceinline__ float bf2f(short s) {
    return __uint_as_float(((unsigned)(unsigned short)s) << 16);
}

// async global->LDS, 16B per lane. ldst must be WAVE-UNIFORM base; HW writes
// lane i's 16B at ldst + i*16 (m97/m104 semantics).
static __device__ __forceinline__ void async_ld16(const void* gsrc, void* ldst) {
    __builtin_amdgcn_global_load_lds(
        (const __attribute__((address_space(1))) unsigned int*)gsrc,
        (__attribute__((address_space(3))) unsigned int*)ldst,
        16, 0, 0);
}

// ---------------------------------------------------------------------------
// Prep: val[i] = emb[poi[i/128]*128 + i%128]; deg init 1 (self loop); fill=0
// ---------------------------------------------------------------------------
__global__ __launch_bounds__(256) void k_prep(const float* __restrict__ feature,
                                              const float* __restrict__ emb,
                                              float* __restrict__ val,
                                              float* __restrict__ deg,
                                              int* __restrict__ fill, int n) {
    int i = blockIdx.x * 256 + threadIdx.x;
    if (i >= n) return;
    int row = i >> 7;
    int ch  = i & 127;
    int id  = (int)feature[row * FF];
    val[i]  = emb[id * CC + ch];
    deg[i]  = 1.0f;
    fill[i] = 0;
}

__global__ __launch_bounds__(256) void k_deg(const int* __restrict__ dst,
                                             float* __restrict__ deg, int e) {
    int i = blockIdx.x * 256 + threadIdx.x;
    if (i >= e) return;
    atomicAdd(&deg[dst[i]], 1.0f);
}

__global__ __launch_bounds__(256) void k_dinv(const float* __restrict__ deg,
                                              float* __restrict__ dinv, int n) {
    int i = blockIdx.x * 256 + threadIdx.x;
    if (i >= n) return;
    dinv[i] = rsqrtf(deg[i]);
}

// ---------------------------------------------------------------------------
// Parallel 3-pass exclusive scan of (deg-1) -> rowptr
// ---------------------------------------------------------------------------
__global__ __launch_bounds__(256) void k_scan1(const float* __restrict__ deg,
                                               int* __restrict__ partial, int n) {
    __shared__ int s[256];
    int i = blockIdx.x * 256 + threadIdx.x;
    int t = threadIdx.x;
    s[t] = (i < n) ? (int)deg[i] - 1 : 0;
    __syncthreads();
    #pragma unroll
    for (int off = 128; off > 0; off >>= 1) {
        if (t < off) s[t] += s[t + off];
        __syncthreads();
    }
    if (t == 0) partial[blockIdx.x] = s[0];
}

__global__ __launch_bounds__(256) void k_scan2(const int* __restrict__ partial,
                                               int* __restrict__ partial_ex, int nb) {
    __shared__ int s[256];
    int t = threadIdx.x;
    s[t] = (t < nb) ? partial[t] : 0;
    __syncthreads();
    #pragma unroll
    for (int off = 1; off < 256; off <<= 1) {
        int v = (t >= off) ? s[t - off] : 0;
        __syncthreads();
        s[t] += v;
        __syncthreads();
    }
    partial_ex[t] = (t == 0) ? 0 : s[t - 1];
}

__global__ __launch_bounds__(256) void k_scan3(const float* __restrict__ deg,
                                               const int* __restrict__ partial_ex,
                                               int* __restrict__ rowptr, int n) {
    __shared__ int s[256];
    int i = blockIdx.x * 256 + threadIdx.x;
    int t = threadIdx.x;
    int d = (i < n) ? (int)deg[i] - 1 : 0;
    s[t] = d;
    __syncthreads();
    #pragma unroll
    for (int off = 1; off < 256; off <<= 1) {
        int v = (t >= off) ? s[t - off] : 0;
        __syncthreads();
        s[t] += v;
        __syncthreads();
    }
    int incl = s[t];
    int base = partial_ex[blockIdx.x];
    if (i < n) rowptr[i] = base + incl - d;
    if (i == n - 1) rowptr[n] = base + incl;
}

__global__ __launch_bounds__(256) void k_fill(const int* __restrict__ src,
                                              const int* __restrict__ dst,
                                              const float* __restrict__ dinv,
                                              const int* __restrict__ rowptr,
                                              int* __restrict__ fill,
                                              int* __restrict__ csr_src,
                                              float* __restrict__ csr_w, int e) {
    int i = blockIdx.x * 256 + threadIdx.x;
    if (i >= e) return;
    int d = dst[i], s = src[i];
    int pos = rowptr[d] + atomicAdd(&fill[d], 1);
    csr_src[pos] = s;
    csr_w[pos]   = dinv[s] * dinv[d];
}

// ---------------------------------------------------------------------------
// B split precompute: W[K][128] fp32 -> Bt_hi/Bt_lo[128][K] bf16 (transposed)
// ---------------------------------------------------------------------------
__global__ __launch_bounds__(256) void k_bsplit(const float* __restrict__ W,
                                                short* __restrict__ Bth,
                                                short* __restrict__ Btl, int K) {
    int idx = blockIdx.x * 256 + threadIdx.x;
    if (idx >= K * 128) return;
    int bn = idx / K, k = idx - bn * K;
    float w = W[k * CC + bn];
    short h = f2bf(w);
    Bth[idx] = h;
    Btl[idx] = f2bf(w - bf2f(h));
}

// ---------------------------------------------------------------------------
// Input GEMM (K=544), BM=16: one-shot staging, ONE barrier, pipelined B.
// r11 post-mortem: all ≤2.3-blocks/CU variants converge to 57us (memory-
// concurrency-bound; r3's 40%-occupancy K-split hit 1.55TB/s). This keeps
// r11's phase-2 (register-pipelined B, unrolled, barrier-free) but shrinks
// LDS to 34.8KB -> 4 blocks/CU, grid 2396 -> 2x resident memory streams.
// LDS frame f = kit*4+sel: 16 rows x 8 shorts (k = kit*32+sel*8 .. +8).
// ---------------------------------------------------------------------------
template <bool SUBST>
__global__ __launch_bounds__(256, 4) void k_gemm544(const float* __restrict__ A,
                                                    const float* __restrict__ val,
                                                    const short* __restrict__ Bth,
                                                    const short* __restrict__ Btl,
                                                    float* __restrict__ H, int n) {
    __shared__ __align__(16) short Ah_s[68 * 128];   // 17.4 KB
    __shared__ __align__(16) short Al_s[68 * 128];   // 17.4 KB

    const int t  = threadIdx.x;
    const int i0 = blockIdx.x * 16;

    // --- Phase 1: stage A hi/lo (16 threads/row, 9 float4 loads each) ---
    {
        const int srow = t >> 4;             // 0..15 (local row)
        const int c4   = t & 15;             // float4 column phase
        int rg = i0 + srow;
        if (rg > n - 1) rg = n - 1;          // clamp pad rows (never stored)
        const float* ap = A + (size_t)rg * FF;
        #pragma unroll
        for (int j = 0; j < 9; j++) {
            int col4 = c4 + 16 * j;          // 0..143
            if (col4 < 136) {
                float4 v = *(const float4*)(ap + col4 * 4);
                if (SUBST && col4 == 0) v.x = val[rg];
                short4 hv, lv;
                hv.x = f2bf(v.x); lv.x = f2bf(v.x - bf2f(hv.x));
                hv.y = f2bf(v.y); lv.y = f2bf(v.y - bf2f(hv.y));
                hv.z = f2bf(v.z); lv.z = f2bf(v.z - bf2f(hv.z));
                hv.w = f2bf(v.w); lv.w = f2bf(v.w - bf2f(hv.w));
                int c0   = col4 * 4;         // float column 0..543
                int kit  = c0 >> 5;
                int sel4 = (c0 >> 3) & 3;
                int pos  = c0 & 7;           // 0 or 4
                int off  = (kit * 4 + sel4) * 128 + srow * 8 + pos;
                *(short4*)&Ah_s[off] = hv;
                *(short4*)&Al_s[off] = lv;
            }
        }
    }

    const int lane = t & 63;
    const int w    = t >> 6;
    const int fr   = lane & 15;
    const int sel  = lane >> 4;

    const short* gb0h = Bth + (size_t)((w * 2 + 0) * 16 + fr) * FF;
    const short* gb0l = Btl + (size_t)((w * 2 + 0) * 16 + fr) * FF;
    const short* gb1h = Bth + (size_t)((w * 2 + 1) * 16 + fr) * FF;
    const short* gb1l = Btl + (size_t)((w * 2 + 1) * 16 + fr) * FF;
    const int so = sel * 8;

    // hoist kit 0 and kit 1 B loads above the barrier (hide under the wait)
    short8v p0b0h = *(const short8v*)(gb0h + so);
    short8v p0b0l = *(const short8v*)(gb0l + so);
    short8v p0b1h = *(const short8v*)(gb1h + so);
    short8v p0b1l = *(const short8v*)(gb1l + so);
    short8v p1b0h = *(const short8v*)(gb0h + 32 + so);
    short8v p1b0l = *(const short8v*)(gb0l + 32 + so);
    short8v p1b1h = *(const short8v*)(gb1h + 32 + so);
    short8v p1b1l = *(const short8v*)(gb1l + 32 + so);

    __syncthreads();                          // the ONLY barrier

    floatx4 acc0 = (floatx4){0.f, 0.f, 0.f, 0.f};
    floatx4 acc1 = (floatx4){0.f, 0.f, 0.f, 0.f};

    #pragma unroll
    for (int kit = 0; kit < 17; kit++) {
        short8v b0h, b0l, b1h, b1l;
        if (kit == 0) {
            b0h = p0b0h; b0l = p0b0l; b1h = p0b1h; b1l = p0b1l;
        } else if (kit == 1) {
            b0h = p1b0h; b0l = p1b0l; b1h = p1b1h; b1l = p1b1l;
        } else {
            const int ko = kit * 32 + so;
            b0h = *(const short8v*)(gb0h + ko);
            b0l = *(const short8v*)(gb0l + ko);
            b1h = *(const short8v*)(gb1h + ko);
            b1l = *(const short8v*)(gb1l + ko);
        }
        const int offA = (kit * 4 + sel) * 128 + fr * 8;
        short8v ah = *(const short8v*)&Ah_s[offA];
        short8v al = *(const short8v*)&Al_s[offA];
        acc0 = __builtin_amdgcn_mfma_f32_16x16x32_bf16(ah, b0h, acc0, 0, 0, 0);
        acc1 = __builtin_amdgcn_mfma_f32_16x16x32_bf16(ah, b1h, acc1, 0, 0, 0);
        acc0 = __builtin_amdgcn_mfma_f32_16x16x32_bf16(ah, b0l, acc0, 0, 0, 0);
        acc1 = __builtin_amdgcn_mfma_f32_16x16x32_bf16(ah, b1l, acc1, 0, 0, 0);
        acc0 = __builtin_amdgcn_mfma_f32_16x16x32_bf16(al, b0h, acc0, 0, 0, 0);
        acc1 = __builtin_amdgcn_mfma_f32_16x16x32_bf16(al, b1h, acc1, 0, 0, 0);
    }

    #pragma unroll
    for (int j = 0; j < 2; j++) {
        floatx4 a = j ? acc1 : acc0;
        int col = (w * 2 + j) * 16 + fr;
        #pragma unroll
        for (int r = 0; r < 4; r++) {
            int row = i0 + sel * 4 + r;
            if (row < n) H[(size_t)row * CC + col] = a[r];
        }
    }
}

// ---------------------------------------------------------------------------
// C-GEMM (K=128), N-SPLIT x2: grid (599, 2) -> 1198 blocks (~4.7 blocks/CU,
// 2x the previous 2.3 which r11 showed is the GEMM bottleneck). Block nh
// covers cols [nh*64, nh*64+64): each wave ONE 16-col tile. A-tile staged
// per block (X read twice: +19.6MB, cheap vs concurrency). Same one-shot
// async_ld16 staging -> ONE barrier -> 48 uninterrupted MFMAs/wave.
// ---------------------------------------------------------------------------
__global__ __launch_bounds__(256) void k_gemm128(const short* __restrict__ Xh,
                                                 const short* __restrict__ Xl,
                                                 const short* __restrict__ Bth,
                                                 const short* __restrict__ Btl,
                                                 float* __restrict__ H, int n) {
    __shared__ __align__(16) short Ah_s[16 * 512];   // 16 KB
    __shared__ __align__(16) short Al_s[16 * 512];   // 16 KB
    const int t    = threadIdx.x;
    const int w    = t >> 6;
    const int lane = t & 63;
    const int fr   = lane & 15;
    const int sel  = lane >> 4;
    const int i0   = blockIdx.x * 64;
    const int nh   = blockIdx.y;             // N-half: cols nh*64 ..

    // --- B fragments -> registers (1 n-tile per wave) ---
    short8v bh[4], bl[4];
    {
        int nidx = (nh * 4 + w) * 16 + fr;
        #pragma unroll
        for (int kit = 0; kit < 4; kit++) {
            bh[kit] = *(const short8v*)&Bth[nidx * 128 + kit * 32 + sel * 8];
            bl[kit] = *(const short8v*)&Btl[nidx * 128 + kit * 32 + sel * 8];
        }
    }

    floatx4 acc[4];
    #pragma unroll
    for (int mt = 0; mt < 4; mt++) acc[mt] = (floatx4){0.f, 0.f, 0.f, 0.f};

    int rA = i0 + lane;
    if (rA > n - 1) rA = n - 1;              // clamp pad rows (never stored)
    const short* gh = Xh + (size_t)rA * 128 + w * 8;
    const short* gl = Xl + (size_t)rA * 128 + w * 8;

    #pragma unroll
    for (int kit = 0; kit < 4; kit++) {
        async_ld16(gh + kit * 32, &Ah_s[(kit * 4 + w) * 512]);
        async_ld16(gl + kit * 32, &Al_s[(kit * 4 + w) * 512]);
    }
    __syncthreads();                          // single drain for all staging

    #pragma unroll
    for (int kit = 0; kit < 4; kit++) {
        short8v ah[4], al[4];
        #pragma unroll
        for (int mt = 0; mt < 4; mt++) {
            int off = (kit * 4 + sel) * 512 + (mt * 16 + fr) * 8;
            ah[mt] = *(const short8v*)&Ah_s[off];
            al[mt] = *(const short8v*)&Al_s[off];
        }
        #pragma unroll
        for (int mt = 0; mt < 4; mt++) {
            acc[mt] = __builtin_amdgcn_mfma_f32_16x16x32_bf16(ah[mt], bh[kit], acc[mt], 0, 0, 0);
            acc[mt] = __builtin_amdgcn_mfma_f32_16x16x32_bf16(ah[mt], bl[kit], acc[mt], 0, 0, 0);
            acc[mt] = __builtin_amdgcn_mfma_f32_16x16x32_bf16(al[mt], bh[kit], acc[mt], 0, 0, 0);
        }
    }

    {
        int col = (nh * 4 + w) * 16 + fr;
        #pragma unroll
        for (int mt = 0; mt < 4; mt++) {
            #pragma unroll
            for (int r = 0; r < 4; r++) {
                int row = i0 + mt * 16 + sel * 4 + r;
                if (row < n) H[(size_t)row * CC + col] = acc[mt][r];
            }
        }
    }
}

// ---------------------------------------------------------------------------
// Row gather v5: 4 rows per 256-thr block (1 wave/row). Wave split into two
// 32-lane halves; float4 per lane; halves merged via __shfl_xor(.,32).
// MODE 0: x = lrelu(t); MODE 1: x = lrelu(t)+t; MODE 2: MODE1 + fused W_out
// dot -> gpre[row].
// ---------------------------------------------------------------------------
template <int MODE>
__global__ __launch_bounds__(256) void k_row(const float* __restrict__ H,
                                             const int* __restrict__ rowptr,
                                             const int* __restrict__ csr_src,
                                             const float* __restrict__ csr_w,
                                             const float* __restrict__ dinv,
                                             const float* __restrict__ bias,
                                             short* __restrict__ Xh,
                                             short* __restrict__ Xl,
                                             const float* __restrict__ Wout,
                                             float* __restrict__ gpre, int n) {
    const int w    = threadIdx.x >> 6;
    const int l    = threadIdx.x & 63;
    const int half = l >> 5;
    const int cl   = l & 31;                 // channels 4cl..4cl+3
    const int row  = blockIdx.x * 4 + w;
    if (row >= n) return;
    const float4* H4 = (const float4*)H;     // [N][32] float4
    float a0 = 0.f, a1 = 0.f, a2 = 0.f, a3 = 0.f;
    if (half == 0) {                         // self-loop + bias only once
        const float di = dinv[row];
        const float dd = di * di;
        float4 b4 = ((const float4*)bias)[cl];
        float4 s4 = H4[(size_t)row * 32 + cl];
        a0 = b4.x + s4.x * dd; a1 = b4.y + s4.y * dd;
        a2 = b4.z + s4.z * dd; a3 = b4.w + s4.w * dd;
    }
    const int rs = rowptr[row], re = rowptr[row + 1];
    for (int base = rs; base < re; base += 64) {
        int m = re - base; if (m > 64) m = 64;
        int myi = 0; float myw = 0.f;
        if (l < m) { myi = csr_src[base + l]; myw = csr_w[base + l]; }
        const int lo = half * 32;
        const int hi = min(m, lo + 32);
        int j = lo;
        for (; j + 4 <= hi; j += 4) {
            int   i0 = __shfl(myi, j, 64),     i1 = __shfl(myi, j + 1, 64);
            int   i2 = __shfl(myi, j + 2, 64), i3 = __shfl(myi, j + 3, 64);
            float w0 = __shfl(myw, j, 64),     w1 = __shfl(myw, j + 1, 64);
            float w2 = __shfl(myw, j + 2, 64), w3 = __shfl(myw, j + 3, 64);
            float4 h0 = H4[(size_t)i0 * 32 + cl];
            float4 h1 = H4[(size_t)i1 * 32 + cl];
            float4 h2 = H4[(size_t)i2 * 32 + cl];
            float4 h3 = H4[(size_t)i3 * 32 + cl];
            a0 += h0.x * w0; a1 += h0.y * w0; a2 += h0.z * w0; a3 += h0.w * w0;
            a0 += h1.x * w1; a1 += h1.y * w1; a2 += h1.z * w1; a3 += h1.w * w1;
            a0 += h2.x * w2; a1 += h2.y * w2; a2 += h2.z * w2; a3 += h2.w * w2;
            a0 += h3.x * w3; a1 += h3.y * w3; a2 += h3.z * w3; a3 += h3.w * w3;
        }
        for (; j < hi; j++) {
            int   idx = __shfl(myi, j, 64);
            float wv  = __shfl(myw, j, 64);
            float4 hv = H4[(size_t)idx * 32 + cl];
            a0 += hv.x * wv; a1 += hv.y * wv; a2 += hv.z * wv; a3 += hv.w * wv;
        }
    }
    // merge the two halves: every lane gets the full channel sums
    a0 += __shfl_xor(a0, 32, 64);
    a1 += __shfl_xor(a1, 32, 64);
    a2 += __shfl_xor(a2, 32, 64);
    a3 += __shfl_xor(a3, 32, 64);
    float r0 = lrelu(a0), r1 = lrelu(a1), r2 = lrelu(a2), r3 = lrelu(a3);
    float x0 = MODE ? (r0 + a0) : r0;
    float x1 = MODE ? (r1 + a1) : r1;
    float x2 = MODE ? (r2 + a2) : r2;
    float x3 = MODE ? (r3 + a3) : r3;
    if (MODE == 2) {
        float4 w4 = ((const float4*)Wout)[cl];
        float p = x0 * w4.x + x1 * w4.y + x2 * w4.z + x3 * w4.w;
        #pragma unroll
        for (int off = 16; off > 0; off >>= 1) p += __shfl_down(p, off, 32);
        if (l == 0) gpre[row] = p;
    } else {
        short h0 = f2bf(x0), h1 = f2bf(x1), h2 = f2bf(x2), h3 = f2bf(x3);
        size_t o = (size_t)row * 128 + cl * 4;
        if (half == 0) {
            *(short4*)&Xh[o] = make_short4(h0, h1, h2, h3);
        } else {
            *(short4*)&Xl[o] = make_short4(f2bf(x0 - bf2f(h0)), f2bf(x1 - bf2f(h1)),
                                           f2bf(x2 - bf2f(h2)), f2bf(x3 - bf2f(h3)));
        }
    }
}

__global__ __launch_bounds__(256) void k_row1(const float* __restrict__ gpre,
                                              const int* __restrict__ rowptr,
                                              const int* __restrict__ csr_src,
                                              const float* __restrict__ csr_w,
                                              const float* __restrict__ dinv,
                                              const float* __restrict__ bout,
                                              float* __restrict__ g, int n) {
    int i = blockIdx.x * 256 + threadIdx.x;
    if (i >= n) return;
    float di = dinv[i];
    float acc = bout[0] + gpre[i] * di * di;
    int e1 = rowptr[i + 1];
    for (int e = rowptr[i]; e < e1; e++)
        acc += gpre[csr_src[e]] * csr_w[e];
    g[i] = lrelu(acc);
}

__global__ void k_hacc_init(const float* __restrict__ bfc1, float* __restrict__ hacc) {
    hacc[threadIdx.x] = bfc1[threadIdx.x];
}

// g[N] @ W_fc1[N,128] : 512 blocks x 256 thr (2 row streams), LDS reduce
__global__ __launch_bounds__(256) void k_fc1(const float* __restrict__ g,
                                             const float* __restrict__ Wfc1,
                                             float* __restrict__ hacc, int n) {
    __shared__ float red[256];
    int c = threadIdx.x & 127;
    int p = threadIdx.x >> 7;
    int nb = gridDim.x;
    int chunk = (n + nb - 1) / nb;
    int s = blockIdx.x * chunk;
    int e = min(n, s + chunk);
    float acc = 0.f;
    for (int i = s + p; i < e; i += 2)
        acc += g[i] * Wfc1[(size_t)i * CC + c];
    red[threadIdx.x] = acc;
    __syncthreads();
    if (p == 0) atomicAdd(&hacc[c], red[c] + red[128 + c]);
}

__global__ __launch_bounds__(256) void k_fc2(const float* __restrict__ hacc,
                                             const float* __restrict__ Wfc2,
                                             const float* __restrict__ bfc2,
                                             float* __restrict__ out, int P) {
    __shared__ float sh[128];
    int t = threadIdx.x;
    if (t < 128) { float v = hacc[t]; sh[t] = v > 0.f ? v : 0.f; }
    __syncthreads();
    int k = blockIdx.x * 256 + t;
    if (k >= P) return;
    float acc = bfc2[k];
    #pragma unroll 8
    for (int j = 0; j < 128; j++)
        acc += sh[j] * Wfc2[(size_t)j * P + k];
    out[k] = acc > 0.f ? acc : 0.f;
}

// ---------------------------------------------------------------------------
extern "C" void kernel_launch(void* const* d_in, const int* in_sizes, int n_in,
                              void* d_out, int out_size, void* d_ws, size_t ws_size,
                              hipStream_t stream) {
    const float* feature = (const float*)d_in[0];
    const int*   eidx  = (const int*)d_in[2];
    const int*   e_src = eidx;
    const int*   e_dst = eidx + EE;
    const float* emb   = (const float*)d_in[3];
    const float* W_in  = (const float*)d_in[4];
    const float* b_in  = (const float*)d_in[5];
    const float* W_gcn = (const float*)d_in[6];
    const float* b_gcn = (const float*)d_in[7];
    const float* W_out = (const float*)d_in[8];
    const float* b_out = (const float*)d_in[9];
    const float* W_fc1 = (const float*)d_in[10];
    const float* b_fc1 = (const float*)d_in[11];
    const float* W_fc2 = (const float*)d_in[12];
    const float* b_fc2 = (const float*)d_in[13];
    float* out = (float*)d_out;

    float* w = (float*)d_ws;
    size_t off = 0;
    auto take = [&](size_t elems) -> float* {
        float* p = w + off;
        off += (elems + 63) & ~(size_t)63;
        return p;
    };
    float* val     = take(NN);
    float* deg     = take(NN);
    float* dinv    = take(NN);
    int*   rowptr  = (int*)take(NN + 1);
    int*   fill    = (int*)take(NN);
    int*   csr_src = (int*)take(EE);
    float* csr_w   = take(EE);
    float* bufH    = take((size_t)NN * CC);             // H (fp32)
    short* Xh      = (short*)take((size_t)NN * CC / 2); // X split hi (bf16)
    short* Xl      = (short*)take((size_t)NN * CC / 2); // X split lo
    float* gpre    = take(NN);
    float* g       = take(NN);
    float* hacc    = take(128);
    short* bt_in_h  = (short*)take(FF * CC / 2);
    short* bt_in_l  = (short*)take(FF * CC / 2);
    short* bt_gcn_h = (short*)take((size_t)LL * CC * CC / 2);
    short* bt_gcn_l = (short*)take((size_t)LL * CC * CC / 2);
    int*   part     = (int*)take(256);
    int*   part_ex  = (int*)take(256);
    (void)ws_size; (void)in_sizes; (void)n_in; (void)out_size;

    const int gN   = (NN + 255) / 256;   // 150
    const int gE   = (EE + 255) / 256;
    const int gBM  = (NN + 63) / 64;     // 599  (k_gemm128 M-tiles)
    const int g544 = (NN + 15) / 16;     // 2396 (k_gemm544, BM=16)
    const int gR   = (NN + 3) / 4;       // k_row: 4 rows per 256-thr block

    // --- weight splits ---
    k_bsplit<<<(FF * CC + 255) / 256, 256, 0, stream>>>(W_in, bt_in_h, bt_in_l, FF);
    for (int l = 0; l < LL; l++)
        k_bsplit<<<(CC * CC + 255) / 256, 256, 0, stream>>>(
            W_gcn + (size_t)l * CC * CC,
            bt_gcn_h + (size_t)l * CC * CC, bt_gcn_l + (size_t)l * CC * CC, CC);

    // --- graph preprocessing: CSR by dst + symmetric norm ---
    k_prep<<<gN, 256, 0, stream>>>(feature, emb, val, deg, fill, NN);
    k_deg<<<gE, 256, 0, stream>>>(e_dst, deg, EE);
    k_dinv<<<gN, 256, 0, stream>>>(deg, dinv, NN);
    k_scan1<<<gN, 256, 0, stream>>>(deg, part, NN);
    k_scan2<<<1, 256, 0, stream>>>(part, part_ex, gN);
    k_scan3<<<gN, 256, 0, stream>>>(deg, part_ex, rowptr, NN);
    k_fill<<<gE, 256, 0, stream>>>(e_src, e_dst, dinv, rowptr, fill,
                                   csr_src, csr_w, EE);

    // --- input layer: BM=16 one-shot GEMM (4 blocks/CU) ---
    k_gemm544<true><<<g544, 256, 0, stream>>>(feature, val,
                                              bt_in_h, bt_in_l, bufH, NN);
    k_row<0><<<gR, 256, 0, stream>>>(bufH, rowptr, csr_src, csr_w, dinv, b_in,
                                     Xh, Xl, nullptr, nullptr, NN);

    // --- 4 GcnUnits (last one fuses the W_out dot -> gpre) ---
    for (int l = 0; l < LL - 1; l++) {
        k_gemm128<<<dim3(gBM, 2), 256, 0, stream>>>(Xh, Xl,
            bt_gcn_h + (size_t)l * CC * CC, bt_gcn_l + (size_t)l * CC * CC,
            bufH, NN);
        k_row<1><<<gR, 256, 0, stream>>>(bufH, rowptr, csr_src, csr_w, dinv,
                                         b_gcn + (size_t)l * CC, Xh, Xl,
                                         nullptr, nullptr, NN);
    }
    k_gemm128<<<dim3(gBM, 2), 256, 0, stream>>>(Xh, Xl,
        bt_gcn_h + (size_t)(LL - 1) * CC * CC,
        bt_gcn_l + (size_t)(LL - 1) * CC * CC, bufH, NN);
    k_row<2><<<gR, 256, 0, stream>>>(bufH, rowptr, csr_src, csr_w, dinv,
                                     b_gcn + (size_t)(LL - 1) * CC,
                                     nullptr, nullptr, W_out, gpre, NN);

    // --- output conv epilogue (C=1 gather) ---
    k_row1<<<gN, 256, 0, stream>>>(gpre, rowptr, csr_src, csr_w, dinv, b_out,
                                   g, NN);

    // --- FC head ---
    k_hacc_init<<<1, 128, 0, stream>>>(b_fc1, hacc);
    k_fc1<<<512, 256, 0, stream>>>(g, W_fc1, hacc, NN);
    k_fc2<<<(PP + 255) / 256, 256, 0, stream>>>(hacc, W_fc2, b_fc2, out, PP);
}

// Round 13
// 652.227 us; speedup vs baseline: 1.0557x; 1.0557x over previous
//
#include <hip/hip_runtime.h>

// Problem constants (from reference)
#define NN 38332          // nodes
#define FF 544            // input features
#define CC 128            // channels
#define LL 4              // gcn layers
#define EE (NN*16)        // edges (613312)
#define PP 38333          // POI_LEN (output size)

typedef __attribute__((ext_vector_type(8))) short short8v;
typedef __attribute__((ext_vector_type(4))) float floatx4;

static __device__ __forceinline__ float lrelu(float x) {
    return x >= 0.f ? x : 0.01f * x;
}

// fp32 -> bf16 round-to-nearest-even (bit trick)
static __device__ __forceinline__ short f2bf(float f) {
    unsigned u = __float_as_uint(f);
    unsigned r = (u + 0x7fffu + ((u >> 16) & 1u)) >> 16;
    return (short)r;
}
static __device__ __forceinline__ float bf2f(short s) {
    return __uint_as_float(((unsigned)(unsigned short)s) << 16);
}

// async global->LDS, 16B per lane. ldst must be WAVE-UNIFORM base; HW writes
// lane i's 16B at ldst + i*16 (m97/m104 semantics).
static __device__ __forceinline__ void async_ld16(const void* gsrc, void* ldst) {
    __builtin_amdgcn_global_load_lds(
        (const __attribute__((address_space(1))) unsigned int*)gsrc,
        (__attribute__((address_space(3))) unsigned int*)ldst,
        16, 0, 0);
}

// ---------------------------------------------------------------------------
// Prep: val[i] = emb[poi[i/128]*128 + i%128]; deg init 1 (self loop); fill=0
// ---------------------------------------------------------------------------
__global__ __launch_bounds__(256) void k_prep(const float* __restrict__ feature,
                                              const float* __restrict__ emb,
                                              float* __restrict__ val,
                                              float* __restrict__ deg,
                                              int* __restrict__ fill, int n) {
    int i = blockIdx.x * 256 + threadIdx.x;
    if (i >= n) return;
    int row = i >> 7;
    int ch  = i & 127;
    int id  = (int)feature[row * FF];
    val[i]  = emb[id * CC + ch];
    deg[i]  = 1.0f;
    fill[i] = 0;
}

__global__ __launch_bounds__(256) void k_deg(const int* __restrict__ dst,
                                             float* __restrict__ deg, int e) {
    int i = blockIdx.x * 256 + threadIdx.x;
    if (i >= e) return;
    atomicAdd(&deg[dst[i]], 1.0f);
}

__global__ __launch_bounds__(256) void k_dinv(const float* __restrict__ deg,
                                              float* __restrict__ dinv, int n) {
    int i = blockIdx.x * 256 + threadIdx.x;
    if (i >= n) return;
    dinv[i] = rsqrtf(deg[i]);
}

// ---------------------------------------------------------------------------
// Parallel 3-pass exclusive scan of (deg-1) -> rowptr
// ---------------------------------------------------------------------------
__global__ __launch_bounds__(256) void k_scan1(const float* __restrict__ deg,
                                               int* __restrict__ partial, int n) {
    __shared__ int s[256];
    int i = blockIdx.x * 256 + threadIdx.x;
    int t = threadIdx.x;
    s[t] = (i < n) ? (int)deg[i] - 1 : 0;
    __syncthreads();
    #pragma unroll
    for (int off = 128; off > 0; off >>= 1) {
        if (t < off) s[t] += s[t + off];
        __syncthreads();
    }
    if (t == 0) partial[blockIdx.x] = s[0];
}

__global__ __launch_bounds__(256) void k_scan2(const int* __restrict__ partial,
                                               int* __restrict__ partial_ex, int nb) {
    __shared__ int s[256];
    int t = threadIdx.x;
    s[t] = (t < nb) ? partial[t] : 0;
    __syncthreads();
    #pragma unroll
    for (int off = 1; off < 256; off <<= 1) {
        int v = (t >= off) ? s[t - off] : 0;
        __syncthreads();
        s[t] += v;
        __syncthreads();
    }
    partial_ex[t] = (t == 0) ? 0 : s[t - 1];
}

__global__ __launch_bounds__(256) void k_scan3(const float* __restrict__ deg,
                                               const int* __restrict__ partial_ex,
                                               int* __restrict__ rowptr, int n) {
    __shared__ int s[256];
    int i = blockIdx.x * 256 + threadIdx.x;
    int t = threadIdx.x;
    int d = (i < n) ? (int)deg[i] - 1 : 0;
    s[t] = d;
    __syncthreads();
    #pragma unroll
    for (int off = 1; off < 256; off <<= 1) {
        int v = (t >= off) ? s[t - off] : 0;
        __syncthreads();
        s[t] += v;
        __syncthreads();
    }
    int incl = s[t];
    int base = partial_ex[blockIdx.x];
    if (i < n) rowptr[i] = base + incl - d;
    if (i == n - 1) rowptr[n] = base + incl;
}

__global__ __launch_bounds__(256) void k_fill(const int* __restrict__ src,
                                              const int* __restrict__ dst,
                                              const float* __restrict__ dinv,
                                              const int* __restrict__ rowptr,
                                              int* __restrict__ fill,
                                              int* __restrict__ csr_src,
                                              float* __restrict__ csr_w, int e) {
    int i = blockIdx.x * 256 + threadIdx.x;
    if (i >= e) return;
    int d = dst[i], s = src[i];
    int pos = rowptr[d] + atomicAdd(&fill[d], 1);
    csr_src[pos] = s;
    csr_w[pos]   = dinv[s] * dinv[d];
}

// ---------------------------------------------------------------------------
// B split precompute: W[K][128] fp32 -> Bt_hi/Bt_lo[128][K] bf16 (transposed)
// ---------------------------------------------------------------------------
__global__ __launch_bounds__(256) void k_bsplit(const float* __restrict__ W,
                                                short* __restrict__ Bth,
                                                short* __restrict__ Btl, int K) {
    int idx = blockIdx.x * 256 + threadIdx.x;
    if (idx >= K * 128) return;
    int bn = idx / K, k = idx - bn * K;
    float w = W[k * CC + bn];
    short h = f2bf(w);
    Bth[idx] = h;
    Btl[idx] = f2bf(w - bf2f(h));
}

// ---------------------------------------------------------------------------
// Input GEMM (K=544) — r11 MEASURED 57.0us version (BM=32, pipelined B,
// VGPR 88). r12 lesson: launch_bounds(256,4)+BM=16 squeezed VGPR to 52 ->
// serial B -> 88us at HIGHER occupancy. Occupancy is not the lever; the
// register-pipelined B loop is. Reverted and frozen.
// ---------------------------------------------------------------------------
template <bool SUBST>
__global__ __launch_bounds__(256, 2) void k_gemm544(const float* __restrict__ A,
                                                    const float* __restrict__ val,
                                                    const short* __restrict__ Bth,
                                                    const short* __restrict__ Btl,
                                                    float* __restrict__ H, int n) {
    __shared__ __align__(16) short Ah_s[68 * 256];   // 34.8 KB
    __shared__ __align__(16) short Al_s[68 * 256];   // 34.8 KB

    const int t  = threadIdx.x;
    const int i0 = blockIdx.x * 32;

    // --- Phase 1: stage A hi/lo (17 independent float4 loads/thread) ---
    {
        const int srow = t >> 3;             // 0..31 (local row)
        const int c4p  = t & 7;              // float4 column phase
        int rg = i0 + srow;
        if (rg > n - 1) rg = n - 1;          // clamp pad rows (never stored)
        const float* ap = A + (size_t)rg * FF;
        #pragma unroll
        for (int j = 0; j < 17; j++) {
            int col4 = c4p + 8 * j;          // 0..135
            float4 v = *(const float4*)(ap + col4 * 4);
            if (SUBST && col4 == 0) v.x = val[rg];
            short4 hv, lv;
            hv.x = f2bf(v.x); lv.x = f2bf(v.x - bf2f(hv.x));
            hv.y = f2bf(v.y); lv.y = f2bf(v.y - bf2f(hv.y));
            hv.z = f2bf(v.z); lv.z = f2bf(v.z - bf2f(hv.z));
            hv.w = f2bf(v.w); lv.w = f2bf(v.w - bf2f(hv.w));
            int c0   = col4 * 4;             // float column 0..543
            int kit  = c0 >> 5;
            int sel4 = (c0 >> 3) & 3;
            int pos  = c0 & 7;               // 0 or 4
            int off  = (kit * 4 + sel4) * 256 + srow * 8 + pos;
            *(short4*)&Ah_s[off] = hv;
            *(short4*)&Al_s[off] = lv;
        }
    }

    const int lane = t & 63;
    const int w    = t >> 6;
    const int fr   = lane & 15;
    const int sel  = lane >> 4;

    const short* gb0h = Bth + (size_t)((w * 2 + 0) * 16 + fr) * FF;
    const short* gb0l = Btl + (size_t)((w * 2 + 0) * 16 + fr) * FF;
    const short* gb1h = Bth + (size_t)((w * 2 + 1) * 16 + fr) * FF;
    const short* gb1l = Btl + (size_t)((w * 2 + 1) * 16 + fr) * FF;
    const int so = sel * 8;

    // hoist kit 0 and kit 1 B loads above the barrier (hide under the wait)
    short8v p0b0h = *(const short8v*)(gb0h + so);
    short8v p0b0l = *(const short8v*)(gb0l + so);
    short8v p0b1h = *(const short8v*)(gb1h + so);
    short8v p0b1l = *(const short8v*)(gb1l + so);
    short8v p1b0h = *(const short8v*)(gb0h + 32 + so);
    short8v p1b0l = *(const short8v*)(gb0l + 32 + so);
    short8v p1b1h = *(const short8v*)(gb1h + 32 + so);
    short8v p1b1l = *(const short8v*)(gb1l + 32 + so);

    __syncthreads();                          // the ONLY barrier

    floatx4 acc[2][2];
    #pragma unroll
    for (int mt = 0; mt < 2; mt++)
        #pragma unroll
        for (int nt = 0; nt < 2; nt++)
            acc[mt][nt] = (floatx4){0.f, 0.f, 0.f, 0.f};

    #pragma unroll
    for (int kit = 0; kit < 17; kit++) {
        short8v b0h, b0l, b1h, b1l;
        if (kit == 0) {
            b0h = p0b0h; b0l = p0b0l; b1h = p0b1h; b1l = p0b1l;
        } else if (kit == 1) {
            b0h = p1b0h; b0l = p1b0l; b1h = p1b1h; b1l = p1b1l;
        } else {
            const int ko = kit * 32 + so;
            b0h = *(const short8v*)(gb0h + ko);
            b0l = *(const short8v*)(gb0l + ko);
            b1h = *(const short8v*)(gb1h + ko);
            b1l = *(const short8v*)(gb1l + ko);
        }
        short8v ah[2], al[2];
        #pragma unroll
        for (int mt = 0; mt < 2; mt++) {
            int offA = (kit * 4 + sel) * 256 + (mt * 16 + fr) * 8;
            ah[mt] = *(const short8v*)&Ah_s[offA];
            al[mt] = *(const short8v*)&Al_s[offA];
        }
        #pragma unroll
        for (int mt = 0; mt < 2; mt++) {
            acc[mt][0] = __builtin_amdgcn_mfma_f32_16x16x32_bf16(ah[mt], b0h, acc[mt][0], 0, 0, 0);
            acc[mt][1] = __builtin_amdgcn_mfma_f32_16x16x32_bf16(ah[mt], b1h, acc[mt][1], 0, 0, 0);
            acc[mt][0] = __builtin_amdgcn_mfma_f32_16x16x32_bf16(ah[mt], b0l, acc[mt][0], 0, 0, 0);
            acc[mt][1] = __builtin_amdgcn_mfma_f32_16x16x32_bf16(ah[mt], b1l, acc[mt][1], 0, 0, 0);
            acc[mt][0] = __builtin_amdgcn_mfma_f32_16x16x32_bf16(al[mt], b0h, acc[mt][0], 0, 0, 0);
            acc[mt][1] = __builtin_amdgcn_mfma_f32_16x16x32_bf16(al[mt], b1h, acc[mt][1], 0, 0, 0);
        }
    }

    #pragma unroll
    for (int mt = 0; mt < 2; mt++)
        #pragma unroll
        for (int nt = 0; nt < 2; nt++) {
            int col = (w * 2 + nt) * 16 + fr;
            #pragma unroll
            for (int r = 0; r < 4; r++) {
                int row = i0 + mt * 16 + sel * 4 + r;
                if (row < n) H[(size_t)row * CC + col] = acc[mt][nt][r];
            }
        }
}

// ---------------------------------------------------------------------------
// C-GEMM (K=128), N-SPLIT x2 (r12, kept: net ~-8us vs r11): grid (599, 2).
// Block nh covers cols [nh*64, +64); each wave ONE 16-col tile. A-tile
// staged per block via async_ld16 -> ONE barrier -> 48 MFMAs/wave.
// ---------------------------------------------------------------------------
__global__ __launch_bounds__(256) void k_gemm128(const short* __restrict__ Xh,
                                                 const short* __restrict__ Xl,
                                                 const short* __restrict__ Bth,
                                                 const short* __restrict__ Btl,
                                                 float* __restrict__ H, int n) {
    __shared__ __align__(16) short Ah_s[16 * 512];   // 16 KB
    __shared__ __align__(16) short Al_s[16 * 512];   // 16 KB
    const int t    = threadIdx.x;
    const int w    = t >> 6;
    const int lane = t & 63;
    const int fr   = lane & 15;
    const int sel  = lane >> 4;
    const int i0   = blockIdx.x * 64;
    const int nh   = blockIdx.y;             // N-half: cols nh*64 ..

    // --- B fragments -> registers (1 n-tile per wave) ---
    short8v bh[4], bl[4];
    {
        int nidx = (nh * 4 + w) * 16 + fr;
        #pragma unroll
        for (int kit = 0; kit < 4; kit++) {
            bh[kit] = *(const short8v*)&Bth[nidx * 128 + kit * 32 + sel * 8];
            bl[kit] = *(const short8v*)&Btl[nidx * 128 + kit * 32 + sel * 8];
        }
    }

    floatx4 acc[4];
    #pragma unroll
    for (int mt = 0; mt < 4; mt++) acc[mt] = (floatx4){0.f, 0.f, 0.f, 0.f};

    int rA = i0 + lane;
    if (rA > n - 1) rA = n - 1;              // clamp pad rows (never stored)
    const short* gh = Xh + (size_t)rA * 128 + w * 8;
    const short* gl = Xl + (size_t)rA * 128 + w * 8;

    #pragma unroll
    for (int kit = 0; kit < 4; kit++) {
        async_ld16(gh + kit * 32, &Ah_s[(kit * 4 + w) * 512]);
        async_ld16(gl + kit * 32, &Al_s[(kit * 4 + w) * 512]);
    }
    __syncthreads();                          // single drain for all staging

    #pragma unroll
    for (int kit = 0; kit < 4; kit++) {
        short8v ah[4], al[4];
        #pragma unroll
        for (int mt = 0; mt < 4; mt++) {
            int off = (kit * 4 + sel) * 512 + (mt * 16 + fr) * 8;
            ah[mt] = *(const short8v*)&Ah_s[off];
            al[mt] = *(const short8v*)&Al_s[off];
        }
        #pragma unroll
        for (int mt = 0; mt < 4; mt++) {
            acc[mt] = __builtin_amdgcn_mfma_f32_16x16x32_bf16(ah[mt], bh[kit], acc[mt], 0, 0, 0);
            acc[mt] = __builtin_amdgcn_mfma_f32_16x16x32_bf16(ah[mt], bl[kit], acc[mt], 0, 0, 0);
            acc[mt] = __builtin_amdgcn_mfma_f32_16x16x32_bf16(al[mt], bh[kit], acc[mt], 0, 0, 0);
        }
    }

    {
        int col = (nh * 4 + w) * 16 + fr;
        #pragma unroll
        for (int mt = 0; mt < 4; mt++) {
            #pragma unroll
            for (int r = 0; r < 4; r++) {
                int row = i0 + mt * 16 + sel * 4 + r;
                if (row < n) H[(size_t)row * CC + col] = acc[mt][r];
            }
        }
    }
}

// ---------------------------------------------------------------------------
// Row gather v6: ONE ROW PER 32-LANE HALF (8 rows / 256-thr block).
// r12 insight: mean degree ~16, so v5's upper 32-edge half did NOTHING for
// nearly every row (32/64 lanes idle through the gather). Now each half
// handles a full row: self-loop + gather (float4/lane over 32 channels,
// 32-edge batches), indices broadcast via __shfl within the half. No
// cross-half merge. 2x useful work per wave + 2x gather MLP.
// MODE 0: x=lrelu(t); MODE 1: x=lrelu(t)+t; MODE 2: MODE1 + fused W_out dot.
// ---------------------------------------------------------------------------
template <int MODE>
__global__ __launch_bounds__(256) void k_row(const float* __restrict__ H,
                                             const int* __restrict__ rowptr,
                                             const int* __restrict__ csr_src,
                                             const float* __restrict__ csr_w,
                                             const float* __restrict__ dinv,
                                             const float* __restrict__ bias,
                                             short* __restrict__ Xh,
                                             short* __restrict__ Xl,
                                             const float* __restrict__ Wout,
                                             float* __restrict__ gpre, int n) {
    const int w    = threadIdx.x >> 6;
    const int l    = threadIdx.x & 63;
    const int half = l >> 5;
    const int cl   = l & 31;                 // channels 4cl..4cl+3
    const int row  = blockIdx.x * 8 + w * 2 + half;
    const bool ok  = (row < n);
    const float4* H4 = (const float4*)H;     // [N][32] float4
    float a0 = 0.f, a1 = 0.f, a2 = 0.f, a3 = 0.f;
    int rs = 0, re = 0;
    if (ok) {
        const float di = dinv[row];
        const float dd = di * di;
        float4 b4 = ((const float4*)bias)[cl];
        float4 s4 = H4[(size_t)row * 32 + cl];
        a0 = b4.x + s4.x * dd; a1 = b4.y + s4.y * dd;
        a2 = b4.z + s4.z * dd; a3 = b4.w + s4.w * dd;
        rs = rowptr[row]; re = rowptr[row + 1];
    }
    for (int base = rs; base < re; base += 32) {
        int m = re - base; if (m > 32) m = 32;
        int myi = 0; float myw = 0.f;
        if (cl < m) { myi = csr_src[base + cl]; myw = csr_w[base + cl]; }
        const int lb = half * 32;            // this half's lane base
        int j = 0;
        for (; j + 4 <= m; j += 4) {
            int   i0 = __shfl(myi, lb + j, 64),     i1 = __shfl(myi, lb + j + 1, 64);
            int   i2 = __shfl(myi, lb + j + 2, 64), i3 = __shfl(myi, lb + j + 3, 64);
            float w0 = __shfl(myw, lb + j, 64),     w1 = __shfl(myw, lb + j + 1, 64);
            float w2 = __shfl(myw, lb + j + 2, 64), w3 = __shfl(myw, lb + j + 3, 64);
            float4 h0 = H4[(size_t)i0 * 32 + cl];
            float4 h1 = H4[(size_t)i1 * 32 + cl];
            float4 h2 = H4[(size_t)i2 * 32 + cl];
            float4 h3 = H4[(size_t)i3 * 32 + cl];
            a0 += h0.x * w0; a1 += h0.y * w0; a2 += h0.z * w0; a3 += h0.w * w0;
            a0 += h1.x * w1; a1 += h1.y * w1; a2 += h1.z * w1; a3 += h1.w * w1;
            a0 += h2.x * w2; a1 += h2.y * w2; a2 += h2.z * w2; a3 += h2.w * w2;
            a0 += h3.x * w3; a1 += h3.y * w3; a2 += h3.z * w3; a3 += h3.w * w3;
        }
        for (; j < m; j++) {
            int   idx = __shfl(myi, lb + j, 64);
            float wv  = __shfl(myw, lb + j, 64);
            float4 hv = H4[(size_t)idx * 32 + cl];
            a0 += hv.x * wv; a1 += hv.y * wv; a2 += hv.z * wv; a3 += hv.w * wv;
        }
    }
    if (!ok) return;
    float r0 = lrelu(a0), r1 = lrelu(a1), r2 = lrelu(a2), r3 = lrelu(a3);
    float x0 = MODE ? (r0 + a0) : r0;
    float x1 = MODE ? (r1 + a1) : r1;
    float x2 = MODE ? (r2 + a2) : r2;
    float x3 = MODE ? (r3 + a3) : r3;
    if (MODE == 2) {
        float4 w4 = ((const float4*)Wout)[cl];
        float p = x0 * w4.x + x1 * w4.y + x2 * w4.z + x3 * w4.w;
        #pragma unroll
        for (int off = 16; off > 0; off >>= 1) p += __shfl_down(p, off, 32);
        if (cl == 0) gpre[row] = p;
    } else {
        short4 hi4 = make_short4(f2bf(x0), f2bf(x1), f2bf(x2), f2bf(x3));
        short4 lo4 = make_short4(f2bf(x0 - bf2f(hi4.x)), f2bf(x1 - bf2f(hi4.y)),
                                 f2bf(x2 - bf2f(hi4.z)), f2bf(x3 - bf2f(hi4.w)));
        size_t o = (size_t)row * 128 + cl * 4;
        *(short4*)&Xh[o] = hi4;
        *(short4*)&Xl[o] = lo4;
    }
}

__global__ __launch_bounds__(256) void k_row1(const float* __restrict__ gpre,
                                              const int* __restrict__ rowptr,
                                              const int* __restrict__ csr_src,
                                              const float* __restrict__ csr_w,
                                              const float* __restrict__ dinv,
                                              const float* __restrict__ bout,
                                              float* __restrict__ g, int n) {
    int i = blockIdx.x * 256 + threadIdx.x;
    if (i >= n) return;
    float di = dinv[i];
    float acc = bout[0] + gpre[i] * di * di;
    int e1 = rowptr[i + 1];
    for (int e = rowptr[i]; e < e1; e++)
        acc += gpre[csr_src[e]] * csr_w[e];
    g[i] = lrelu(acc);
}

__global__ void k_hacc_init(const float* __restrict__ bfc1, float* __restrict__ hacc) {
    hacc[threadIdx.x] = bfc1[threadIdx.x];
}

// g[N] @ W_fc1[N,128] : 512 blocks x 256 thr (2 row streams), LDS reduce
__global__ __launch_bounds__(256) void k_fc1(const float* __restrict__ g,
                                             const float* __restrict__ Wfc1,
                                             float* __restrict__ hacc, int n) {
    __shared__ float red[256];
    int c = threadIdx.x & 127;
    int p = threadIdx.x >> 7;
    int nb = gridDim.x;
    int chunk = (n + nb - 1) / nb;
    int s = blockIdx.x * chunk;
    int e = min(n, s + chunk);
    float acc = 0.f;
    for (int i = s + p; i < e; i += 2)
        acc += g[i] * Wfc1[(size_t)i * CC + c];
    red[threadIdx.x] = acc;
    __syncthreads();
    if (p == 0) atomicAdd(&hacc[c], red[c] + red[128 + c]);
}

__global__ __launch_bounds__(256) void k_fc2(const float* __restrict__ hacc,
                                             const float* __restrict__ Wfc2,
                                             const float* __restrict__ bfc2,
                                             float* __restrict__ out, int P) {
    __shared__ float sh[128];
    int t = threadIdx.x;
    if (t < 128) { float v = hacc[t]; sh[t] = v > 0.f ? v : 0.f; }
    __syncthreads();
    int k = blockIdx.x * 256 + t;
    if (k >= P) return;
    float acc = bfc2[k];
    #pragma unroll 8
    for (int j = 0; j < 128; j++)
        acc += sh[j] * Wfc2[(size_t)j * P + k];
    out[k] = acc > 0.f ? acc : 0.f;
}

// ---------------------------------------------------------------------------
extern "C" void kernel_launch(void* const* d_in, const int* in_sizes, int n_in,
                              void* d_out, int out_size, void* d_ws, size_t ws_size,
                              hipStream_t stream) {
    const float* feature = (const float*)d_in[0];
    const int*   eidx  = (const int*)d_in[2];
    const int*   e_src = eidx;
    const int*   e_dst = eidx + EE;
    const float* emb   = (const float*)d_in[3];
    const float* W_in  = (const float*)d_in[4];
    const float* b_in  = (const float*)d_in[5];
    const float* W_gcn = (const float*)d_in[6];
    const float* b_gcn = (const float*)d_in[7];
    const float* W_out = (const float*)d_in[8];
    const float* b_out = (const float*)d_in[9];
    const float* W_fc1 = (const float*)d_in[10];
    const float* b_fc1 = (const float*)d_in[11];
    const float* W_fc2 = (const float*)d_in[12];
    const float* b_fc2 = (const float*)d_in[13];
    float* out = (float*)d_out;

    float* w = (float*)d_ws;
    size_t off = 0;
    auto take = [&](size_t elems) -> float* {
        float* p = w + off;
        off += (elems + 63) & ~(size_t)63;
        return p;
    };
    float* val     = take(NN);
    float* deg     = take(NN);
    float* dinv    = take(NN);
    int*   rowptr  = (int*)take(NN + 1);
    int*   fill    = (int*)take(NN);
    int*   csr_src = (int*)take(EE);
    float* csr_w   = take(EE);
    float* bufH    = take((size_t)NN * CC);             // H (fp32)
    short* Xh      = (short*)take((size_t)NN * CC / 2); // X split hi (bf16)
    short* Xl      = (short*)take((size_t)NN * CC / 2); // X split lo
    float* gpre    = take(NN);
    float* g       = take(NN);
    float* hacc    = take(128);
    short* bt_in_h  = (short*)take(FF * CC / 2);
    short* bt_in_l  = (short*)take(FF * CC / 2);
    short* bt_gcn_h = (short*)take((size_t)LL * CC * CC / 2);
    short* bt_gcn_l = (short*)take((size_t)LL * CC * CC / 2);
    int*   part     = (int*)take(256);
    int*   part_ex  = (int*)take(256);
    (void)ws_size; (void)in_sizes; (void)n_in; (void)out_size;

    const int gN   = (NN + 255) / 256;   // 150
    const int gE   = (EE + 255) / 256;
    const int gBM  = (NN + 63) / 64;     // 599  (k_gemm128 M-tiles)
    const int g544 = (NN + 31) / 32;     // 1198 (k_gemm544, BM=32)
    const int gR   = (NN + 7) / 8;       // k_row: 8 rows per 256-thr block

    // --- weight splits ---
    k_bsplit<<<(FF * CC + 255) / 256, 256, 0, stream>>>(W_in, bt_in_h, bt_in_l, FF);
    for (int l = 0; l < LL; l++)
        k_bsplit<<<(CC * CC + 255) / 256, 256, 0, stream>>>(
            W_gcn + (size_t)l * CC * CC,
            bt_gcn_h + (size_t)l * CC * CC, bt_gcn_l + (size_t)l * CC * CC, CC);

    // --- graph preprocessing: CSR by dst + symmetric norm ---
    k_prep<<<gN, 256, 0, stream>>>(feature, emb, val, deg, fill, NN);
    k_deg<<<gE, 256, 0, stream>>>(e_dst, deg, EE);
    k_dinv<<<gN, 256, 0, stream>>>(deg, dinv, NN);
    k_scan1<<<gN, 256, 0, stream>>>(deg, part, NN);
    k_scan2<<<1, 256, 0, stream>>>(part, part_ex, gN);
    k_scan3<<<gN, 256, 0, stream>>>(deg, part_ex, rowptr, NN);
    k_fill<<<gE, 256, 0, stream>>>(e_src, e_dst, dinv, rowptr, fill,
                                   csr_src, csr_w, EE);

    // --- input layer: r11 BM=32 one-shot GEMM (57.0us measured) ---
    k_gemm544<true><<<g544, 256, 0, stream>>>(feature, val,
                                              bt_in_h, bt_in_l, bufH, NN);
    k_row<0><<<gR, 256, 0, stream>>>(bufH, rowptr, csr_src, csr_w, dinv, b_in,
                                     Xh, Xl, nullptr, nullptr, NN);

    // --- 4 GcnUnits (last one fuses the W_out dot -> gpre) ---
    for (int l = 0; l < LL - 1; l++) {
        k_gemm128<<<dim3(gBM, 2), 256, 0, stream>>>(Xh, Xl,
            bt_gcn_h + (size_t)l * CC * CC, bt_gcn_l + (size_t)l * CC * CC,
            bufH, NN);
        k_row<1><<<gR, 256, 0, stream>>>(bufH, rowptr, csr_src, csr_w, dinv,
                                         b_gcn + (size_t)l * CC, Xh, Xl,
                                         nullptr, nullptr, NN);
    }
    k_gemm128<<<dim3(gBM, 2), 256, 0, stream>>>(Xh, Xl,
        bt_gcn_h + (size_t)(LL - 1) * CC * CC,
        bt_gcn_l + (size_t)(LL - 1) * CC * CC, bufH, NN);
    k_row<2><<<gR, 256, 0, stream>>>(bufH, rowptr, csr_src, csr_w, dinv,
                                     b_gcn + (size_t)(LL - 1) * CC,
                                     nullptr, nullptr, W_out, gpre, NN);

    // --- output conv epilogue (C=1 gather) ---
    k_row1<<<gN, 256, 0, stream>>>(gpre, rowptr, csr_src, csr_w, dinv, b_out,
                                   g, NN);

    // --- FC head ---
    k_hacc_init<<<1, 128, 0, stream>>>(b_fc1, hacc);
    k_fc1<<<512, 256, 0, stream>>>(g, W_fc1, hacc, NN);
    k_fc2<<<(PP + 255) / 256, 256, 0, stream>>>(hacc, W_fc2, b_fc2, out, PP);
}

// Round 14
// 549.002 us; speedup vs baseline: 1.2542x; 1.1880x over previous
//
#include <hip/hip_runtime.h>

// Problem constants (from reference)
#define NN 38332          // nodes
#define FF 544            // input features
#define CC 128            // channels
#define LL 4              // gcn layers
#define EE (NN*16)        // edges (613312)
#define PP 38333          // POI_LEN (output size)

typedef __attribute__((ext_vector_type(8))) short short8v;
typedef __attribute__((ext_vector_type(4))) float floatx4;

static __device__ __forceinline__ float lrelu(float x) {
    return x >= 0.f ? x : 0.01f * x;
}

// fp32 -> bf16 round-to-nearest-even (bit trick)
static __device__ __forceinline__ short f2bf(float f) {
    unsigned u = __float_as_uint(f);
    unsigned r = (u + 0x7fffu + ((u >> 16) & 1u)) >> 16;
    return (short)r;
}
static __device__ __forceinline__ float bf2f(short s) {
    return __uint_as_float(((unsigned)(unsigned short)s) << 16);
}

// async global->LDS, 16B per lane. ldst must be WAVE-UNIFORM base; HW writes
// lane i's 16B at ldst + i*16 (m97/m104 semantics).
static __device__ __forceinline__ void async_ld16(const void* gsrc, void* ldst) {
    __builtin_amdgcn_global_load_lds(
        (const __attribute__((address_space(1))) unsigned int*)gsrc,
        (__attribute__((address_space(3))) unsigned int*)ldst,
        16, 0, 0);
}

// ---------------------------------------------------------------------------
// Prep: val[i] = emb[poi[i/128]*128 + i%128]; deg init 1 (self loop); fill=0
// ---------------------------------------------------------------------------
__global__ __launch_bounds__(256) void k_prep(const float* __restrict__ feature,
                                              const float* __restrict__ emb,
                                              float* __restrict__ val,
                                              float* __restrict__ deg,
                                              int* __restrict__ fill, int n) {
    int i = blockIdx.x * 256 + threadIdx.x;
    if (i >= n) return;
    int row = i >> 7;
    int ch  = i & 127;
    int id  = (int)feature[row * FF];
    val[i]  = emb[id * CC + ch];
    deg[i]  = 1.0f;
    fill[i] = 0;
}

__global__ __launch_bounds__(256) void k_deg(const int* __restrict__ dst,
                                             float* __restrict__ deg, int e) {
    int i = blockIdx.x * 256 + threadIdx.x;
    if (i >= e) return;
    atomicAdd(&deg[dst[i]], 1.0f);
}

__global__ __launch_bounds__(256) void k_dinv(const float* __restrict__ deg,
                                              float* __restrict__ dinv, int n) {
    int i = blockIdx.x * 256 + threadIdx.x;
    if (i >= n) return;
    dinv[i] = rsqrtf(deg[i]);
}

// ---------------------------------------------------------------------------
// Parallel 3-pass exclusive scan of (deg-1) -> rowptr
// ---------------------------------------------------------------------------
__global__ __launch_bounds__(256) void k_scan1(const float* __restrict__ deg,
                                               int* __restrict__ partial, int n) {
    __shared__ int s[256];
    int i = blockIdx.x * 256 + threadIdx.x;
    int t = threadIdx.x;
    s[t] = (i < n) ? (int)deg[i] - 1 : 0;
    __syncthreads();
    #pragma unroll
    for (int off = 128; off > 0; off >>= 1) {
        if (t < off) s[t] += s[t + off];
        __syncthreads();
    }
    if (t == 0) partial[blockIdx.x] = s[0];
}

__global__ __launch_bounds__(256) void k_scan2(const int* __restrict__ partial,
                                               int* __restrict__ partial_ex, int nb) {
    __shared__ int s[256];
    int t = threadIdx.x;
    s[t] = (t < nb) ? partial[t] : 0;
    __syncthreads();
    #pragma unroll
    for (int off = 1; off < 256; off <<= 1) {
        int v = (t >= off) ? s[t - off] : 0;
        __syncthreads();
        s[t] += v;
        __syncthreads();
    }
    partial_ex[t] = (t == 0) ? 0 : s[t - 1];
}

__global__ __launch_bounds__(256) void k_scan3(const float* __restrict__ deg,
                                               const int* __restrict__ partial_ex,
                                               int* __restrict__ rowptr, int n) {
    __shared__ int s[256];
    int i = blockIdx.x * 256 + threadIdx.x;
    int t = threadIdx.x;
    int d = (i < n) ? (int)deg[i] - 1 : 0;
    s[t] = d;
    __syncthreads();
    #pragma unroll
    for (int off = 1; off < 256; off <<= 1) {
        int v = (t >= off) ? s[t - off] : 0;
        __syncthreads();
        s[t] += v;
        __syncthreads();
    }
    int incl = s[t];
    int base = partial_ex[blockIdx.x];
    if (i < n) rowptr[i] = base + incl - d;
    if (i == n - 1) rowptr[n] = base + incl;
}

__global__ __launch_bounds__(256) void k_fill(const int* __restrict__ src,
                                              const int* __restrict__ dst,
                                              const float* __restrict__ dinv,
                                              const int* __restrict__ rowptr,
                                              int* __restrict__ fill,
                                              int* __restrict__ csr_src,
                                              float* __restrict__ csr_w, int e) {
    int i = blockIdx.x * 256 + threadIdx.x;
    if (i >= e) return;
    int d = dst[i], s = src[i];
    int pos = rowptr[d] + atomicAdd(&fill[d], 1);
    csr_src[pos] = s;
    csr_w[pos]   = dinv[s] * dinv[d];
}

// ---------------------------------------------------------------------------
// B split precompute: W[K][128] fp32 -> Bt_hi/Bt_lo[128][K] bf16 (transposed)
// ---------------------------------------------------------------------------
__global__ __launch_bounds__(256) void k_bsplit(const float* __restrict__ W,
                                                short* __restrict__ Bth,
                                                short* __restrict__ Btl, int K) {
    int idx = blockIdx.x * 256 + threadIdx.x;
    if (idx >= K * 128) return;
    int bn = idx / K, k = idx - bn * K;
    float w = W[k * CC + bn];
    short h = f2bf(w);
    Bth[idx] = h;
    Btl[idx] = f2bf(w - bf2f(h));
}

// ---------------------------------------------------------------------------
// Input GEMM (K=544) — r11 MEASURED 57.0us structure (BM=32, pipelined B,
// VGPR 88), frozen. ONLY change: H store is now bf16-hi (Hb) — r13 theory:
// k_row gather is L3-BW-bound, so H goes bf16 to halve gather bytes.
// ---------------------------------------------------------------------------
template <bool SUBST>
__global__ __launch_bounds__(256, 2) void k_gemm544(const float* __restrict__ A,
                                                    const float* __restrict__ val,
                                                    const short* __restrict__ Bth,
                                                    const short* __restrict__ Btl,
                                                    short* __restrict__ Hb, int n) {
    __shared__ __align__(16) short Ah_s[68 * 256];   // 34.8 KB
    __shared__ __align__(16) short Al_s[68 * 256];   // 34.8 KB

    const int t  = threadIdx.x;
    const int i0 = blockIdx.x * 32;

    // --- Phase 1: stage A hi/lo (17 independent float4 loads/thread) ---
    {
        const int srow = t >> 3;             // 0..31 (local row)
        const int c4p  = t & 7;              // float4 column phase
        int rg = i0 + srow;
        if (rg > n - 1) rg = n - 1;          // clamp pad rows (never stored)
        const float* ap = A + (size_t)rg * FF;
        #pragma unroll
        for (int j = 0; j < 17; j++) {
            int col4 = c4p + 8 * j;          // 0..135
            float4 v = *(const float4*)(ap + col4 * 4);
            if (SUBST && col4 == 0) v.x = val[rg];
            short4 hv, lv;
            hv.x = f2bf(v.x); lv.x = f2bf(v.x - bf2f(hv.x));
            hv.y = f2bf(v.y); lv.y = f2bf(v.y - bf2f(hv.y));
            hv.z = f2bf(v.z); lv.z = f2bf(v.z - bf2f(hv.z));
            hv.w = f2bf(v.w); lv.w = f2bf(v.w - bf2f(hv.w));
            int c0   = col4 * 4;             // float column 0..543
            int kit  = c0 >> 5;
            int sel4 = (c0 >> 3) & 3;
            int pos  = c0 & 7;               // 0 or 4
            int off  = (kit * 4 + sel4) * 256 + srow * 8 + pos;
            *(short4*)&Ah_s[off] = hv;
            *(short4*)&Al_s[off] = lv;
        }
    }

    const int lane = t & 63;
    const int w    = t >> 6;
    const int fr   = lane & 15;
    const int sel  = lane >> 4;

    const short* gb0h = Bth + (size_t)((w * 2 + 0) * 16 + fr) * FF;
    const short* gb0l = Btl + (size_t)((w * 2 + 0) * 16 + fr) * FF;
    const short* gb1h = Bth + (size_t)((w * 2 + 1) * 16 + fr) * FF;
    const short* gb1l = Btl + (size_t)((w * 2 + 1) * 16 + fr) * FF;
    const int so = sel * 8;

    // hoist kit 0 and kit 1 B loads above the barrier (hide under the wait)
    short8v p0b0h = *(const short8v*)(gb0h + so);
    short8v p0b0l = *(const short8v*)(gb0l + so);
    short8v p0b1h = *(const short8v*)(gb1h + so);
    short8v p0b1l = *(const short8v*)(gb1l + so);
    short8v p1b0h = *(const short8v*)(gb0h + 32 + so);
    short8v p1b0l = *(const short8v*)(gb0l + 32 + so);
    short8v p1b1h = *(const short8v*)(gb1h + 32 + so);
    short8v p1b1l = *(const short8v*)(gb1l + 32 + so);

    __syncthreads();                          // the ONLY barrier

    floatx4 acc[2][2];
    #pragma unroll
    for (int mt = 0; mt < 2; mt++)
        #pragma unroll
        for (int nt = 0; nt < 2; nt++)
            acc[mt][nt] = (floatx4){0.f, 0.f, 0.f, 0.f};

    #pragma unroll
    for (int kit = 0; kit < 17; kit++) {
        short8v b0h, b0l, b1h, b1l;
        if (kit == 0) {
            b0h = p0b0h; b0l = p0b0l; b1h = p0b1h; b1l = p0b1l;
        } else if (kit == 1) {
            b0h = p1b0h; b0l = p1b0l; b1h = p1b1h; b1l = p1b1l;
        } else {
            const int ko = kit * 32 + so;
            b0h = *(const short8v*)(gb0h + ko);
            b0l = *(const short8v*)(gb0l + ko);
            b1h = *(const short8v*)(gb1h + ko);
            b1l = *(const short8v*)(gb1l + ko);
        }
        short8v ah[2], al[2];
        #pragma unroll
        for (int mt = 0; mt < 2; mt++) {
            int offA = (kit * 4 + sel) * 256 + (mt * 16 + fr) * 8;
            ah[mt] = *(const short8v*)&Ah_s[offA];
            al[mt] = *(const short8v*)&Al_s[offA];
        }
        #pragma unroll
        for (int mt = 0; mt < 2; mt++) {
            acc[mt][0] = __builtin_amdgcn_mfma_f32_16x16x32_bf16(ah[mt], b0h, acc[mt][0], 0, 0, 0);
            acc[mt][1] = __builtin_amdgcn_mfma_f32_16x16x32_bf16(ah[mt], b1h, acc[mt][1], 0, 0, 0);
            acc[mt][0] = __builtin_amdgcn_mfma_f32_16x16x32_bf16(ah[mt], b0l, acc[mt][0], 0, 0, 0);
            acc[mt][1] = __builtin_amdgcn_mfma_f32_16x16x32_bf16(ah[mt], b1l, acc[mt][1], 0, 0, 0);
            acc[mt][0] = __builtin_amdgcn_mfma_f32_16x16x32_bf16(al[mt], b0h, acc[mt][0], 0, 0, 0);
            acc[mt][1] = __builtin_amdgcn_mfma_f32_16x16x32_bf16(al[mt], b1h, acc[mt][1], 0, 0, 0);
        }
    }

    #pragma unroll
    for (int mt = 0; mt < 2; mt++)
        #pragma unroll
        for (int nt = 0; nt < 2; nt++) {
            int col = (w * 2 + nt) * 16 + fr;
            #pragma unroll
            for (int r = 0; r < 4; r++) {
                int row = i0 + mt * 16 + sel * 4 + r;
                if (row < n) Hb[(size_t)row * CC + col] = f2bf(acc[mt][nt][r]);
            }
        }
}

// ---------------------------------------------------------------------------
// C-GEMM (K=128), N-SPLIT x2 (r12/13): grid (599, 2). Block nh covers cols
// [nh*64, +64); each wave ONE 16-col tile. A-tile staged via async_ld16 ->
// ONE barrier -> 48 MFMAs/wave. H store now bf16-hi (Hb).
// ---------------------------------------------------------------------------
__global__ __launch_bounds__(256) void k_gemm128(const short* __restrict__ Xh,
                                                 const short* __restrict__ Xl,
                                                 const short* __restrict__ Bth,
                                                 const short* __restrict__ Btl,
                                                 short* __restrict__ Hb, int n) {
    __shared__ __align__(16) short Ah_s[16 * 512];   // 16 KB
    __shared__ __align__(16) short Al_s[16 * 512];   // 16 KB
    const int t    = threadIdx.x;
    const int w    = t >> 6;
    const int lane = t & 63;
    const int fr   = lane & 15;
    const int sel  = lane >> 4;
    const int i0   = blockIdx.x * 64;
    const int nh   = blockIdx.y;             // N-half: cols nh*64 ..

    // --- B fragments -> registers (1 n-tile per wave) ---
    short8v bh[4], bl[4];
    {
        int nidx = (nh * 4 + w) * 16 + fr;
        #pragma unroll
        for (int kit = 0; kit < 4; kit++) {
            bh[kit] = *(const short8v*)&Bth[nidx * 128 + kit * 32 + sel * 8];
            bl[kit] = *(const short8v*)&Btl[nidx * 128 + kit * 32 + sel * 8];
        }
    }

    floatx4 acc[4];
    #pragma unroll
    for (int mt = 0; mt < 4; mt++) acc[mt] = (floatx4){0.f, 0.f, 0.f, 0.f};

    int rA = i0 + lane;
    if (rA > n - 1) rA = n - 1;              // clamp pad rows (never stored)
    const short* gh = Xh + (size_t)rA * 128 + w * 8;
    const short* gl = Xl + (size_t)rA * 128 + w * 8;

    #pragma unroll
    for (int kit = 0; kit < 4; kit++) {
        async_ld16(gh + kit * 32, &Ah_s[(kit * 4 + w) * 512]);
        async_ld16(gl + kit * 32, &Al_s[(kit * 4 + w) * 512]);
    }
    __syncthreads();                          // single drain for all staging

    #pragma unroll
    for (int kit = 0; kit < 4; kit++) {
        short8v ah[4], al[4];
        #pragma unroll
        for (int mt = 0; mt < 4; mt++) {
            int off = (kit * 4 + sel) * 512 + (mt * 16 + fr) * 8;
            ah[mt] = *(const short8v*)&Ah_s[off];
            al[mt] = *(const short8v*)&Al_s[off];
        }
        #pragma unroll
        for (int mt = 0; mt < 4; mt++) {
            acc[mt] = __builtin_amdgcn_mfma_f32_16x16x32_bf16(ah[mt], bh[kit], acc[mt], 0, 0, 0);
            acc[mt] = __builtin_amdgcn_mfma_f32_16x16x32_bf16(ah[mt], bl[kit], acc[mt], 0, 0, 0);
            acc[mt] = __builtin_amdgcn_mfma_f32_16x16x32_bf16(al[mt], bh[kit], acc[mt], 0, 0, 0);
        }
    }

    {
        int col = (nh * 4 + w) * 16 + fr;
        #pragma unroll
        for (int mt = 0; mt < 4; mt++) {
            #pragma unroll
            for (int r = 0; r < 4; r++) {
                int row = i0 + mt * 16 + sel * 4 + r;
                if (row < n) Hb[(size_t)row * CC + col] = f2bf(acc[mt][r]);
            }
        }
    }
}

// ---------------------------------------------------------------------------
// Row gather v7: v6 structure (one row per 32-lane half, 8 rows/block) but
// gathers from BF16 Hb (256B/row, short4/lane) — r13 showed the gather is
// L3-BW-bound, so halving bytes is the lever. fp32 accumulate.
// MODE 0: x=lrelu(t); MODE 1: x=lrelu(t)+t; MODE 2: MODE1 + fused W_out dot.
// ---------------------------------------------------------------------------
template <int MODE>
__global__ __launch_bounds__(256) void k_row(const short* __restrict__ Hb,
                                             const int* __restrict__ rowptr,
                                             const int* __restrict__ csr_src,
                                             const float* __restrict__ csr_w,
                                             const float* __restrict__ dinv,
                                             const float* __restrict__ bias,
                                             short* __restrict__ Xh,
                                             short* __restrict__ Xl,
                                             const float* __restrict__ Wout,
                                             float* __restrict__ gpre, int n) {
    const int w    = threadIdx.x >> 6;
    const int l    = threadIdx.x & 63;
    const int half = l >> 5;
    const int cl   = l & 31;                 // channels 4cl..4cl+3
    const int row  = blockIdx.x * 8 + w * 2 + half;
    const bool ok  = (row < n);
    const short4* Hb4 = (const short4*)Hb;   // [N][32] short4
    float a0 = 0.f, a1 = 0.f, a2 = 0.f, a3 = 0.f;
    int rs = 0, re = 0;
    if (ok) {
        const float di = dinv[row];
        const float dd = di * di;
        float4 b4 = ((const float4*)bias)[cl];
        short4 s4 = Hb4[(size_t)row * 32 + cl];
        a0 = b4.x + bf2f(s4.x) * dd; a1 = b4.y + bf2f(s4.y) * dd;
        a2 = b4.z + bf2f(s4.z) * dd; a3 = b4.w + bf2f(s4.w) * dd;
        rs = rowptr[row]; re = rowptr[row + 1];
    }
    for (int base = rs; base < re; base += 32) {
        int m = re - base; if (m > 32) m = 32;
        int myi = 0; float myw = 0.f;
        if (cl < m) { myi = csr_src[base + cl]; myw = csr_w[base + cl]; }
        const int lb = half * 32;            // this half's lane base
        int j = 0;
        for (; j + 4 <= m; j += 4) {
            int   i0 = __shfl(myi, lb + j, 64),     i1 = __shfl(myi, lb + j + 1, 64);
            int   i2 = __shfl(myi, lb + j + 2, 64), i3 = __shfl(myi, lb + j + 3, 64);
            float w0 = __shfl(myw, lb + j, 64),     w1 = __shfl(myw, lb + j + 1, 64);
            float w2 = __shfl(myw, lb + j + 2, 64), w3 = __shfl(myw, lb + j + 3, 64);
            short4 h0 = Hb4[(size_t)i0 * 32 + cl];
            short4 h1 = Hb4[(size_t)i1 * 32 + cl];
            short4 h2 = Hb4[(size_t)i2 * 32 + cl];
            short4 h3 = Hb4[(size_t)i3 * 32 + cl];
            a0 += bf2f(h0.x) * w0; a1 += bf2f(h0.y) * w0; a2 += bf2f(h0.z) * w0; a3 += bf2f(h0.w) * w0;
            a0 += bf2f(h1.x) * w1; a1 += bf2f(h1.y) * w1; a2 += bf2f(h1.z) * w1; a3 += bf2f(h1.w) * w1;
            a0 += bf2f(h2.x) * w2; a1 += bf2f(h2.y) * w2; a2 += bf2f(h2.z) * w2; a3 += bf2f(h2.w) * w2;
            a0 += bf2f(h3.x) * w3; a1 += bf2f(h3.y) * w3; a2 += bf2f(h3.z) * w3; a3 += bf2f(h3.w) * w3;
        }
        for (; j < m; j++) {
            int   idx = __shfl(myi, lb + j, 64);
            float wv  = __shfl(myw, lb + j, 64);
            short4 hv = Hb4[(size_t)idx * 32 + cl];
            a0 += bf2f(hv.x) * wv; a1 += bf2f(hv.y) * wv;
            a2 += bf2f(hv.z) * wv; a3 += bf2f(hv.w) * wv;
        }
    }
    if (!ok) return;
    float r0 = lrelu(a0), r1 = lrelu(a1), r2 = lrelu(a2), r3 = lrelu(a3);
    float x0 = MODE ? (r0 + a0) : r0;
    float x1 = MODE ? (r1 + a1) : r1;
    float x2 = MODE ? (r2 + a2) : r2;
    float x3 = MODE ? (r3 + a3) : r3;
    if (MODE == 2) {
        float4 w4 = ((const float4*)Wout)[cl];
        float p = x0 * w4.x + x1 * w4.y + x2 * w4.z + x3 * w4.w;
        #pragma unroll
        for (int off = 16; off > 0; off >>= 1) p += __shfl_down(p, off, 32);
        if (cl == 0) gpre[row] = p;
    } else {
        short4 hi4 = make_short4(f2bf(x0), f2bf(x1), f2bf(x2), f2bf(x3));
        short4 lo4 = make_short4(f2bf(x0 - bf2f(hi4.x)), f2bf(x1 - bf2f(hi4.y)),
                                 f2bf(x2 - bf2f(hi4.z)), f2bf(x3 - bf2f(hi4.w)));
        size_t o = (size_t)row * 128 + cl * 4;
        *(short4*)&Xh[o] = hi4;
        *(short4*)&Xl[o] = lo4;
    }
}

__global__ __launch_bounds__(256) void k_row1(const float* __restrict__ gpre,
                                              const int* __restrict__ rowptr,
                                              const int* __restrict__ csr_src,
                                              const float* __restrict__ csr_w,
                                              const float* __restrict__ dinv,
                                              const float* __restrict__ bout,
                                              float* __restrict__ g, int n) {
    int i = blockIdx.x * 256 + threadIdx.x;
    if (i >= n) return;
    float di = dinv[i];
    float acc = bout[0] + gpre[i] * di * di;
    int e1 = rowptr[i + 1];
    for (int e = rowptr[i]; e < e1; e++)
        acc += gpre[csr_src[e]] * csr_w[e];
    g[i] = lrelu(acc);
}

__global__ void k_hacc_init(const float* __restrict__ bfc1, float* __restrict__ hacc) {
    hacc[threadIdx.x] = bfc1[threadIdx.x];
}

// g[N] @ W_fc1[N,128] : 512 blocks x 256 thr (2 row streams), LDS reduce
__global__ __launch_bounds__(256) void k_fc1(const float* __restrict__ g,
                                             const float* __restrict__ Wfc1,
                                             float* __restrict__ hacc, int n) {
    __shared__ float red[256];
    int c = threadIdx.x & 127;
    int p = threadIdx.x >> 7;
    int nb = gridDim.x;
    int chunk = (n + nb - 1) / nb;
    int s = blockIdx.x * chunk;
    int e = min(n, s + chunk);
    float acc = 0.f;
    for (int i = s + p; i < e; i += 2)
        acc += g[i] * Wfc1[(size_t)i * CC + c];
    red[threadIdx.x] = acc;
    __syncthreads();
    if (p == 0) atomicAdd(&hacc[c], red[c] + red[128 + c]);
}

__global__ __launch_bounds__(256) void k_fc2(const float* __restrict__ hacc,
                                             const float* __restrict__ Wfc2,
                                             const float* __restrict__ bfc2,
                                             float* __restrict__ out, int P) {
    __shared__ float sh[128];
    int t = threadIdx.x;
    if (t < 128) { float v = hacc[t]; sh[t] = v > 0.f ? v : 0.f; }
    __syncthreads();
    int k = blockIdx.x * 256 + t;
    if (k >= P) return;
    float acc = bfc2[k];
    #pragma unroll 8
    for (int j = 0; j < 128; j++)
        acc += sh[j] * Wfc2[(size_t)j * P + k];
    out[k] = acc > 0.f ? acc : 0.f;
}

// ---------------------------------------------------------------------------
extern "C" void kernel_launch(void* const* d_in, const int* in_sizes, int n_in,
                              void* d_out, int out_size, void* d_ws, size_t ws_size,
                              hipStream_t stream) {
    const float* feature = (const float*)d_in[0];
    const int*   eidx  = (const int*)d_in[2];
    const int*   e_src = eidx;
    const int*   e_dst = eidx + EE;
    const float* emb   = (const float*)d_in[3];
    const float* W_in  = (const float*)d_in[4];
    const float* b_in  = (const float*)d_in[5];
    const float* W_gcn = (const float*)d_in[6];
    const float* b_gcn = (const float*)d_in[7];
    const float* W_out = (const float*)d_in[8];
    const float* b_out = (const float*)d_in[9];
    const float* W_fc1 = (const float*)d_in[10];
    const float* b_fc1 = (const float*)d_in[11];
    const float* W_fc2 = (const float*)d_in[12];
    const float* b_fc2 = (const float*)d_in[13];
    float* out = (float*)d_out;

    float* w = (float*)d_ws;
    size_t off = 0;
    auto take = [&](size_t elems) -> float* {
        float* p = w + off;
        off += (elems + 63) & ~(size_t)63;
        return p;
    };
    float* val     = take(NN);
    float* deg     = take(NN);
    float* dinv    = take(NN);
    int*   rowptr  = (int*)take(NN + 1);
    int*   fill    = (int*)take(NN);
    int*   csr_src = (int*)take(EE);
    float* csr_w   = take(EE);
    short* bufHb   = (short*)take((size_t)NN * CC / 2); // H (bf16 hi)
    short* Xh      = (short*)take((size_t)NN * CC / 2); // X split hi (bf16)
    short* Xl      = (short*)take((size_t)NN * CC / 2); // X split lo
    float* gpre    = take(NN);
    float* g       = take(NN);
    float* hacc    = take(128);
    short* bt_in_h  = (short*)take(FF * CC / 2);
    short* bt_in_l  = (short*)take(FF * CC / 2);
    short* bt_gcn_h = (short*)take((size_t)LL * CC * CC / 2);
    short* bt_gcn_l = (short*)take((size_t)LL * CC * CC / 2);
    int*   part     = (int*)take(256);
    int*   part_ex  = (int*)take(256);
    (void)ws_size; (void)in_sizes; (void)n_in; (void)out_size;

    const int gN   = (NN + 255) / 256;   // 150
    const int gE   = (EE + 255) / 256;
    const int gBM  = (NN + 63) / 64;     // 599  (k_gemm128 M-tiles)
    const int g544 = (NN + 31) / 32;     // 1198 (k_gemm544, BM=32)
    const int gR   = (NN + 7) / 8;       // k_row: 8 rows per 256-thr block

    // --- weight splits ---
    k_bsplit<<<(FF * CC + 255) / 256, 256, 0, stream>>>(W_in, bt_in_h, bt_in_l, FF);
    for (int l = 0; l < LL; l++)
        k_bsplit<<<(CC * CC + 255) / 256, 256, 0, stream>>>(
            W_gcn + (size_t)l * CC * CC,
            bt_gcn_h + (size_t)l * CC * CC, bt_gcn_l + (size_t)l * CC * CC, CC);

    // --- graph preprocessing: CSR by dst + symmetric norm ---
    k_prep<<<gN, 256, 0, stream>>>(feature, emb, val, deg, fill, NN);
    k_deg<<<gE, 256, 0, stream>>>(e_dst, deg, EE);
    k_dinv<<<gN, 256, 0, stream>>>(deg, dinv, NN);
    k_scan1<<<gN, 256, 0, stream>>>(deg, part, NN);
    k_scan2<<<1, 256, 0, stream>>>(part, part_ex, gN);
    k_scan3<<<gN, 256, 0, stream>>>(deg, part_ex, rowptr, NN);
    k_fill<<<gE, 256, 0, stream>>>(e_src, e_dst, dinv, rowptr, fill,
                                   csr_src, csr_w, EE);

    // --- input layer: r11 BM=32 one-shot GEMM (bf16 H store) ---
    k_gemm544<true><<<g544, 256, 0, stream>>>(feature, val,
                                              bt_in_h, bt_in_l, bufHb, NN);
    k_row<0><<<gR, 256, 0, stream>>>(bufHb, rowptr, csr_src, csr_w, dinv, b_in,
                                     Xh, Xl, nullptr, nullptr, NN);

    // --- 4 GcnUnits (last one fuses the W_out dot -> gpre) ---
    for (int l = 0; l < LL - 1; l++) {
        k_gemm128<<<dim3(gBM, 2), 256, 0, stream>>>(Xh, Xl,
            bt_gcn_h + (size_t)l * CC * CC, bt_gcn_l + (size_t)l * CC * CC,
            bufHb, NN);
        k_row<1><<<gR, 256, 0, stream>>>(bufHb, rowptr, csr_src, csr_w, dinv,
                                         b_gcn + (size_t)l * CC, Xh, Xl,
                                         nullptr, nullptr, NN);
    }
    k_gemm128<<<dim3(gBM, 2), 256, 0, stream>>>(Xh, Xl,
        bt_gcn_h + (size_t)(LL - 1) * CC * CC,
        bt_gcn_l + (size_t)(LL - 1) * CC * CC, bufHb, NN);
    k_row<2><<<gR, 256, 0, stream>>>(bufHb, rowptr, csr_src, csr_w, dinv,
                                     b_gcn + (size_t)(LL - 1) * CC,
                                     nullptr, nullptr, W_out, gpre, NN);

    // --- output conv epilogue (C=1 gather) ---
    k_row1<<<gN, 256, 0, stream>>>(gpre, rowptr, csr_src, csr_w, dinv, b_out,
                                   g, NN);

    // --- FC head ---
    k_hacc_init<<<1, 128, 0, stream>>>(b_fc1, hacc);
    k_fc1<<<512, 256, 0, stream>>>(g, W_fc1, hacc, NN);
    k_fc2<<<(PP + 255) / 256, 256, 0, stream>>>(hacc, W_fc2, b_fc2, out, PP);
}

// Round 15
// 541.906 us; speedup vs baseline: 1.2706x; 1.0131x over previous
//
#include <hip/hip_runtime.h>

// Problem constants (from reference)
#define NN 38332          // nodes
#define FF 544            // input features
#define CC 128            // channels
#define LL 4              // gcn layers
#define EE (NN*16)        // edges (613312)
#define PP 38333          // POI_LEN (output size)

typedef __attribute__((ext_vector_type(8))) short short8v;
typedef __attribute__((ext_vector_type(4))) float floatx4;

static __device__ __forceinline__ float lrelu(float x) {
    return x >= 0.f ? x : 0.01f * x;
}

// fp32 -> bf16 round-to-nearest-even (bit trick)
static __device__ __forceinline__ short f2bf(float f) {
    unsigned u = __float_as_uint(f);
    unsigned r = (u + 0x7fffu + ((u >> 16) & 1u)) >> 16;
    return (short)r;
}
static __device__ __forceinline__ float bf2f(short s) {
    return __uint_as_float(((unsigned)(unsigned short)s) << 16);
}

// async global->LDS, 16B per lane. ldst must be WAVE-UNIFORM base; HW writes
// lane i's 16B at ldst + i*16 (m97/m104 semantics).
static __device__ __forceinline__ void async_ld16(const void* gsrc, void* ldst) {
    __builtin_amdgcn_global_load_lds(
        (const __attribute__((address_space(1))) unsigned int*)gsrc,
        (__attribute__((address_space(3))) unsigned int*)ldst,
        16, 0, 0);
}

// ---------------------------------------------------------------------------
// Prep: val[i] = emb[poi[i/128]*128 + i%128]; deg init 1 (self loop); fill=0
// ---------------------------------------------------------------------------
__global__ __launch_bounds__(256) void k_prep(const float* __restrict__ feature,
                                              const float* __restrict__ emb,
                                              float* __restrict__ val,
                                              float* __restrict__ deg,
                                              int* __restrict__ fill, int n) {
    int i = blockIdx.x * 256 + threadIdx.x;
    if (i >= n) return;
    int row = i >> 7;
    int ch  = i & 127;
    int id  = (int)feature[row * FF];
    val[i]  = emb[id * CC + ch];
    deg[i]  = 1.0f;
    fill[i] = 0;
}

__global__ __launch_bounds__(256) void k_deg(const int* __restrict__ dst,
                                             float* __restrict__ deg, int e) {
    int i = blockIdx.x * 256 + threadIdx.x;
    if (i >= e) return;
    atomicAdd(&deg[dst[i]], 1.0f);
}

__global__ __launch_bounds__(256) void k_dinv(const float* __restrict__ deg,
                                              float* __restrict__ dinv, int n) {
    int i = blockIdx.x * 256 + threadIdx.x;
    if (i >= n) return;
    dinv[i] = rsqrtf(deg[i]);
}

// ---------------------------------------------------------------------------
// Parallel 3-pass exclusive scan of (deg-1) -> rowptr
// ---------------------------------------------------------------------------
__global__ __launch_bounds__(256) void k_scan1(const float* __restrict__ deg,
                                               int* __restrict__ partial, int n) {
    __shared__ int s[256];
    int i = blockIdx.x * 256 + threadIdx.x;
    int t = threadIdx.x;
    s[t] = (i < n) ? (int)deg[i] - 1 : 0;
    __syncthreads();
    #pragma unroll
    for (int off = 128; off > 0; off >>= 1) {
        if (t < off) s[t] += s[t + off];
        __syncthreads();
    }
    if (t == 0) partial[blockIdx.x] = s[0];
}

__global__ __launch_bounds__(256) void k_scan2(const int* __restrict__ partial,
                                               int* __restrict__ partial_ex, int nb) {
    __shared__ int s[256];
    int t = threadIdx.x;
    s[t] = (t < nb) ? partial[t] : 0;
    __syncthreads();
    #pragma unroll
    for (int off = 1; off < 256; off <<= 1) {
        int v = (t >= off) ? s[t - off] : 0;
        __syncthreads();
        s[t] += v;
        __syncthreads();
    }
    partial_ex[t] = (t == 0) ? 0 : s[t - 1];
}

__global__ __launch_bounds__(256) void k_scan3(const float* __restrict__ deg,
                                               const int* __restrict__ partial_ex,
                                               int* __restrict__ rowptr, int n) {
    __shared__ int s[256];
    int i = blockIdx.x * 256 + threadIdx.x;
    int t = threadIdx.x;
    int d = (i < n) ? (int)deg[i] - 1 : 0;
    s[t] = d;
    __syncthreads();
    #pragma unroll
    for (int off = 1; off < 256; off <<= 1) {
        int v = (t >= off) ? s[t - off] : 0;
        __syncthreads();
        s[t] += v;
        __syncthreads();
    }
    int incl = s[t];
    int base = partial_ex[blockIdx.x];
    if (i < n) rowptr[i] = base + incl - d;
    if (i == n - 1) rowptr[n] = base + incl;
}

__global__ __launch_bounds__(256) void k_fill(const int* __restrict__ src,
                                              const int* __restrict__ dst,
                                              const float* __restrict__ dinv,
                                              const int* __restrict__ rowptr,
                                              int* __restrict__ fill,
                                              int* __restrict__ csr_src,
                                              float* __restrict__ csr_w, int e) {
    int i = blockIdx.x * 256 + threadIdx.x;
    if (i >= e) return;
    int d = dst[i], s = src[i];
    int pos = rowptr[d] + atomicAdd(&fill[d], 1);
    csr_src[pos] = s;
    csr_w[pos]   = dinv[s] * dinv[d];
}

// ---------------------------------------------------------------------------
// B split precompute: W[K][128] fp32 -> Bt_hi/Bt_lo[128][K] bf16 (transposed)
// B keeps hi/lo (weights at ~fp24); A/X lo-halves dropped in r15.
// ---------------------------------------------------------------------------
__global__ __launch_bounds__(256) void k_bsplit(const float* __restrict__ W,
                                                short* __restrict__ Bth,
                                                short* __restrict__ Btl, int K) {
    int idx = blockIdx.x * 256 + threadIdx.x;
    if (idx >= K * 128) return;
    int bn = idx / K, k = idx - bn * K;
    float w = W[k * CC + bn];
    short h = f2bf(w);
    Bth[idx] = h;
    Btl[idx] = f2bf(w - bf2f(h));
}

// ---------------------------------------------------------------------------
// Input GEMM (K=544), BM=32, pipelined B (r11 structure) with A as bf16-hi
// ONLY: LDS 69.6->34.8KB => 4 blocks/CU while keeping the register-pipelined
// B loop (VGPR ~88 fits 4 waves/SIMD). First config combining the two
// proven levers (r3: concurrency helps; r11/r12: pipelined B required).
// MFMAs 4/kit/mt (was 6). H store bf16 (r14).
// ---------------------------------------------------------------------------
template <bool SUBST>
__global__ __launch_bounds__(256, 2) void k_gemm544(const float* __restrict__ A,
                                                    const float* __restrict__ val,
                                                    const short* __restrict__ Bth,
                                                    const short* __restrict__ Btl,
                                                    short* __restrict__ Hb, int n) {
    __shared__ __align__(16) short Ah_s[68 * 256];   // 34.8 KB (hi only)

    const int t  = threadIdx.x;
    const int i0 = blockIdx.x * 32;

    // --- Phase 1: stage A hi (17 independent float4 loads/thread) ---
    {
        const int srow = t >> 3;             // 0..31 (local row)
        const int c4p  = t & 7;              // float4 column phase
        int rg = i0 + srow;
        if (rg > n - 1) rg = n - 1;          // clamp pad rows (never stored)
        const float* ap = A + (size_t)rg * FF;
        #pragma unroll
        for (int j = 0; j < 17; j++) {
            int col4 = c4p + 8 * j;          // 0..135
            float4 v = *(const float4*)(ap + col4 * 4);
            if (SUBST && col4 == 0) v.x = val[rg];
            short4 hv;
            hv.x = f2bf(v.x); hv.y = f2bf(v.y);
            hv.z = f2bf(v.z); hv.w = f2bf(v.w);
            int c0   = col4 * 4;             // float column 0..543
            int kit  = c0 >> 5;
            int sel4 = (c0 >> 3) & 3;
            int pos  = c0 & 7;               // 0 or 4
            int off  = (kit * 4 + sel4) * 256 + srow * 8 + pos;
            *(short4*)&Ah_s[off] = hv;
        }
    }

    const int lane = t & 63;
    const int w    = t >> 6;
    const int fr   = lane & 15;
    const int sel  = lane >> 4;

    const short* gb0h = Bth + (size_t)((w * 2 + 0) * 16 + fr) * FF;
    const short* gb0l = Btl + (size_t)((w * 2 + 0) * 16 + fr) * FF;
    const short* gb1h = Bth + (size_t)((w * 2 + 1) * 16 + fr) * FF;
    const short* gb1l = Btl + (size_t)((w * 2 + 1) * 16 + fr) * FF;
    const int so = sel * 8;

    // hoist kit 0 and kit 1 B loads above the barrier (hide under the wait)
    short8v p0b0h = *(const short8v*)(gb0h + so);
    short8v p0b0l = *(const short8v*)(gb0l + so);
    short8v p0b1h = *(const short8v*)(gb1h + so);
    short8v p0b1l = *(const short8v*)(gb1l + so);
    short8v p1b0h = *(const short8v*)(gb0h + 32 + so);
    short8v p1b0l = *(const short8v*)(gb0l + 32 + so);
    short8v p1b1h = *(const short8v*)(gb1h + 32 + so);
    short8v p1b1l = *(const short8v*)(gb1l + 32 + so);

    __syncthreads();                          // the ONLY barrier

    floatx4 acc[2][2];
    #pragma unroll
    for (int mt = 0; mt < 2; mt++)
        #pragma unroll
        for (int nt = 0; nt < 2; nt++)
            acc[mt][nt] = (floatx4){0.f, 0.f, 0.f, 0.f};

    #pragma unroll
    for (int kit = 0; kit < 17; kit++) {
        short8v b0h, b0l, b1h, b1l;
        if (kit == 0) {
            b0h = p0b0h; b0l = p0b0l; b1h = p0b1h; b1l = p0b1l;
        } else if (kit == 1) {
            b0h = p1b0h; b0l = p1b0l; b1h = p1b1h; b1l = p1b1l;
        } else {
            const int ko = kit * 32 + so;
            b0h = *(const short8v*)(gb0h + ko);
            b0l = *(const short8v*)(gb0l + ko);
            b1h = *(const short8v*)(gb1h + ko);
            b1l = *(const short8v*)(gb1l + ko);
        }
        short8v ah[2];
        #pragma unroll
        for (int mt = 0; mt < 2; mt++) {
            int offA = (kit * 4 + sel) * 256 + (mt * 16 + fr) * 8;
            ah[mt] = *(const short8v*)&Ah_s[offA];
        }
        #pragma unroll
        for (int mt = 0; mt < 2; mt++) {
            acc[mt][0] = __builtin_amdgcn_mfma_f32_16x16x32_bf16(ah[mt], b0h, acc[mt][0], 0, 0, 0);
            acc[mt][1] = __builtin_amdgcn_mfma_f32_16x16x32_bf16(ah[mt], b1h, acc[mt][1], 0, 0, 0);
            acc[mt][0] = __builtin_amdgcn_mfma_f32_16x16x32_bf16(ah[mt], b0l, acc[mt][0], 0, 0, 0);
            acc[mt][1] = __builtin_amdgcn_mfma_f32_16x16x32_bf16(ah[mt], b1l, acc[mt][1], 0, 0, 0);
        }
    }

    #pragma unroll
    for (int mt = 0; mt < 2; mt++)
        #pragma unroll
        for (int nt = 0; nt < 2; nt++) {
            int col = (w * 2 + nt) * 16 + fr;
            #pragma unroll
            for (int r = 0; r < 4; r++) {
                int row = i0 + mt * 16 + sel * 4 + r;
                if (row < n) Hb[(size_t)row * CC + col] = f2bf(acc[mt][nt][r]);
            }
        }
}

// ---------------------------------------------------------------------------
// C-GEMM (K=128), N-SPLIT x2, X as bf16-hi ONLY: A-staging halves (4
// async_ld16/wave, LDS 16KB), 2 MFMAs/kit/mt (a·bh + a·bl). Hb store bf16.
// ---------------------------------------------------------------------------
__global__ __launch_bounds__(256) void k_gemm128(const short* __restrict__ Xh,
                                                 const short* __restrict__ Bth,
                                                 const short* __restrict__ Btl,
                                                 short* __restrict__ Hb, int n) {
    __shared__ __align__(16) short Ah_s[16 * 512];   // 16 KB
    const int t    = threadIdx.x;
    const int w    = t >> 6;
    const int lane = t & 63;
    const int fr   = lane & 15;
    const int sel  = lane >> 4;
    const int i0   = blockIdx.x * 64;
    const int nh   = blockIdx.y;             // N-half: cols nh*64 ..

    // --- B fragments -> registers (1 n-tile per wave) ---
    short8v bh[4], bl[4];
    {
        int nidx = (nh * 4 + w) * 16 + fr;
        #pragma unroll
        for (int kit = 0; kit < 4; kit++) {
            bh[kit] = *(const short8v*)&Bth[nidx * 128 + kit * 32 + sel * 8];
            bl[kit] = *(const short8v*)&Btl[nidx * 128 + kit * 32 + sel * 8];
        }
    }

    floatx4 acc[4];
    #pragma unroll
    for (int mt = 0; mt < 4; mt++) acc[mt] = (floatx4){0.f, 0.f, 0.f, 0.f};

    int rA = i0 + lane;
    if (rA > n - 1) rA = n - 1;              // clamp pad rows (never stored)
    const short* gh = Xh + (size_t)rA * 128 + w * 8;

    #pragma unroll
    for (int kit = 0; kit < 4; kit++)
        async_ld16(gh + kit * 32, &Ah_s[(kit * 4 + w) * 512]);
    __syncthreads();                          // single drain for all staging

    #pragma unroll
    for (int kit = 0; kit < 4; kit++) {
        short8v ah[4];
        #pragma unroll
        for (int mt = 0; mt < 4; mt++) {
            int off = (kit * 4 + sel) * 512 + (mt * 16 + fr) * 8;
            ah[mt] = *(const short8v*)&Ah_s[off];
        }
        #pragma unroll
        for (int mt = 0; mt < 4; mt++) {
            acc[mt] = __builtin_amdgcn_mfma_f32_16x16x32_bf16(ah[mt], bh[kit], acc[mt], 0, 0, 0);
            acc[mt] = __builtin_amdgcn_mfma_f32_16x16x32_bf16(ah[mt], bl[kit], acc[mt], 0, 0, 0);
        }
    }

    {
        int col = (nh * 4 + w) * 16 + fr;
        #pragma unroll
        for (int mt = 0; mt < 4; mt++) {
            #pragma unroll
            for (int r = 0; r < 4; r++) {
                int row = i0 + mt * 16 + sel * 4 + r;
                if (row < n) Hb[(size_t)row * CC + col] = f2bf(acc[mt][r]);
            }
        }
    }
}

// ---------------------------------------------------------------------------
// Row gather v8: v7 structure (one row per 32-lane half, 8 rows/block, bf16
// Hb gather) but writes X as bf16-hi ONLY (no Xl).
// MODE 0: x=lrelu(t); MODE 1: x=lrelu(t)+t; MODE 2: MODE1 + fused W_out dot.
// ---------------------------------------------------------------------------
template <int MODE>
__global__ __launch_bounds__(256) void k_row(const short* __restrict__ Hb,
                                             const int* __restrict__ rowptr,
                                             const int* __restrict__ csr_src,
                                             const float* __restrict__ csr_w,
                                             const float* __restrict__ dinv,
                                             const float* __restrict__ bias,
                                             short* __restrict__ Xh,
                                             const float* __restrict__ Wout,
                                             float* __restrict__ gpre, int n) {
    const int w    = threadIdx.x >> 6;
    const int l    = threadIdx.x & 63;
    const int half = l >> 5;
    const int cl   = l & 31;                 // channels 4cl..4cl+3
    const int row  = blockIdx.x * 8 + w * 2 + half;
    const bool ok  = (row < n);
    const short4* Hb4 = (const short4*)Hb;   // [N][32] short4
    float a0 = 0.f, a1 = 0.f, a2 = 0.f, a3 = 0.f;
    int rs = 0, re = 0;
    if (ok) {
        const float di = dinv[row];
        const float dd = di * di;
        float4 b4 = ((const float4*)bias)[cl];
        short4 s4 = Hb4[(size_t)row * 32 + cl];
        a0 = b4.x + bf2f(s4.x) * dd; a1 = b4.y + bf2f(s4.y) * dd;
        a2 = b4.z + bf2f(s4.z) * dd; a3 = b4.w + bf2f(s4.w) * dd;
        rs = rowptr[row]; re = rowptr[row + 1];
    }
    for (int base = rs; base < re; base += 32) {
        int m = re - base; if (m > 32) m = 32;
        int myi = 0; float myw = 0.f;
        if (cl < m) { myi = csr_src[base + cl]; myw = csr_w[base + cl]; }
        const int lb = half * 32;            // this half's lane base
        int j = 0;
        for (; j + 4 <= m; j += 4) {
            int   i0 = __shfl(myi, lb + j, 64),     i1 = __shfl(myi, lb + j + 1, 64);
            int   i2 = __shfl(myi, lb + j + 2, 64), i3 = __shfl(myi, lb + j + 3, 64);
            float w0 = __shfl(myw, lb + j, 64),     w1 = __shfl(myw, lb + j + 1, 64);
            float w2 = __shfl(myw, lb + j + 2, 64), w3 = __shfl(myw, lb + j + 3, 64);
            short4 h0 = Hb4[(size_t)i0 * 32 + cl];
            short4 h1 = Hb4[(size_t)i1 * 32 + cl];
            short4 h2 = Hb4[(size_t)i2 * 32 + cl];
            short4 h3 = Hb4[(size_t)i3 * 32 + cl];
            a0 += bf2f(h0.x) * w0; a1 += bf2f(h0.y) * w0; a2 += bf2f(h0.z) * w0; a3 += bf2f(h0.w) * w0;
            a0 += bf2f(h1.x) * w1; a1 += bf2f(h1.y) * w1; a2 += bf2f(h1.z) * w1; a3 += bf2f(h1.w) * w1;
            a0 += bf2f(h2.x) * w2; a1 += bf2f(h2.y) * w2; a2 += bf2f(h2.z) * w2; a3 += bf2f(h2.w) * w2;
            a0 += bf2f(h3.x) * w3; a1 += bf2f(h3.y) * w3; a2 += bf2f(h3.z) * w3; a3 += bf2f(h3.w) * w3;
        }
        for (; j < m; j++) {
            int   idx = __shfl(myi, lb + j, 64);
            float wv  = __shfl(myw, lb + j, 64);
            short4 hv = Hb4[(size_t)idx * 32 + cl];
            a0 += bf2f(hv.x) * wv; a1 += bf2f(hv.y) * wv;
            a2 += bf2f(hv.z) * wv; a3 += bf2f(hv.w) * wv;
        }
    }
    if (!ok) return;
    float r0 = lrelu(a0), r1 = lrelu(a1), r2 = lrelu(a2), r3 = lrelu(a3);
    float x0 = MODE ? (r0 + a0) : r0;
    float x1 = MODE ? (r1 + a1) : r1;
    float x2 = MODE ? (r2 + a2) : r2;
    float x3 = MODE ? (r3 + a3) : r3;
    if (MODE == 2) {
        float4 w4 = ((const float4*)Wout)[cl];
        float p = x0 * w4.x + x1 * w4.y + x2 * w4.z + x3 * w4.w;
        #pragma unroll
        for (int off = 16; off > 0; off >>= 1) p += __shfl_down(p, off, 32);
        if (cl == 0) gpre[row] = p;
    } else {
        short4 hi4 = make_short4(f2bf(x0), f2bf(x1), f2bf(x2), f2bf(x3));
        size_t o = (size_t)row * 128 + cl * 4;
        *(short4*)&Xh[o] = hi4;
    }
}

__global__ __launch_bounds__(256) void k_row1(const float* __restrict__ gpre,
                                              const int* __restrict__ rowptr,
                                              const int* __restrict__ csr_src,
                                              const float* __restrict__ csr_w,
                                              const float* __restrict__ dinv,
                                              const float* __restrict__ bout,
                                              float* __restrict__ g, int n) {
    int i = blockIdx.x * 256 + threadIdx.x;
    if (i >= n) return;
    float di = dinv[i];
    float acc = bout[0] + gpre[i] * di * di;
    int e1 = rowptr[i + 1];
    for (int e = rowptr[i]; e < e1; e++)
        acc += gpre[csr_src[e]] * csr_w[e];
    g[i] = lrelu(acc);
}

__global__ void k_hacc_init(const float* __restrict__ bfc1, float* __restrict__ hacc) {
    hacc[threadIdx.x] = bfc1[threadIdx.x];
}

// g[N] @ W_fc1[N,128] : 512 blocks x 256 thr (2 row streams), LDS reduce
__global__ __launch_bounds__(256) void k_fc1(const float* __restrict__ g,
                                             const float* __restrict__ Wfc1,
                                             float* __restrict__ hacc, int n) {
    __shared__ float red[256];
    int c = threadIdx.x & 127;
    int p = threadIdx.x >> 7;
    int nb = gridDim.x;
    int chunk = (n + nb - 1) / nb;
    int s = blockIdx.x * chunk;
    int e = min(n, s + chunk);
    float acc = 0.f;
    for (int i = s + p; i < e; i += 2)
        acc += g[i] * Wfc1[(size_t)i * CC + c];
    red[threadIdx.x] = acc;
    __syncthreads();
    if (p == 0) atomicAdd(&hacc[c], red[c] + red[128 + c]);
}

__global__ __launch_bounds__(256) void k_fc2(const float* __restrict__ hacc,
                                             const float* __restrict__ Wfc2,
                                             const float* __restrict__ bfc2,
                                             float* __restrict__ out, int P) {
    __shared__ float sh[128];
    int t = threadIdx.x;
    if (t < 128) { float v = hacc[t]; sh[t] = v > 0.f ? v : 0.f; }
    __syncthreads();
    int k = blockIdx.x * 256 + t;
    if (k >= P) return;
    float acc = bfc2[k];
    #pragma unroll 8
    for (int j = 0; j < 128; j++)
        acc += sh[j] * Wfc2[(size_t)j * P + k];
    out[k] = acc > 0.f ? acc : 0.f;
}

// ---------------------------------------------------------------------------
extern "C" void kernel_launch(void* const* d_in, const int* in_sizes, int n_in,
                              void* d_out, int out_size, void* d_ws, size_t ws_size,
                              hipStream_t stream) {
    const float* feature = (const float*)d_in[0];
    const int*   eidx  = (const int*)d_in[2];
    const int*   e_src = eidx;
    const int*   e_dst = eidx + EE;
    const float* emb   = (const float*)d_in[3];
    const float* W_in  = (const float*)d_in[4];
    const float* b_in  = (const float*)d_in[5];
    const float* W_gcn = (const float*)d_in[6];
    const float* b_gcn = (const float*)d_in[7];
    const float* W_out = (const float*)d_in[8];
    const float* b_out = (const float*)d_in[9];
    const float* W_fc1 = (const float*)d_in[10];
    const float* b_fc1 = (const float*)d_in[11];
    const float* W_fc2 = (const float*)d_in[12];
    const float* b_fc2 = (const float*)d_in[13];
    float* out = (float*)d_out;

    float* w = (float*)d_ws;
    size_t off = 0;
    auto take = [&](size_t elems) -> float* {
        float* p = w + off;
        off += (elems + 63) & ~(size_t)63;
        return p;
    };
    float* val     = take(NN);
    float* deg     = take(NN);
    float* dinv    = take(NN);
    int*   rowptr  = (int*)take(NN + 1);
    int*   fill    = (int*)take(NN);
    int*   csr_src = (int*)take(EE);
    float* csr_w   = take(EE);
    short* bufHb   = (short*)take((size_t)NN * CC / 2); // H (bf16 hi)
    short* Xh      = (short*)take((size_t)NN * CC / 2); // X (bf16 hi only)
    float* gpre    = take(NN);
    float* g       = take(NN);
    float* hacc    = take(128);
    short* bt_in_h  = (short*)take(FF * CC / 2);
    short* bt_in_l  = (short*)take(FF * CC / 2);
    short* bt_gcn_h = (short*)take((size_t)LL * CC * CC / 2);
    short* bt_gcn_l = (short*)take((size_t)LL * CC * CC / 2);
    int*   part     = (int*)take(256);
    int*   part_ex  = (int*)take(256);
    (void)ws_size; (void)in_sizes; (void)n_in; (void)out_size;

    const int gN   = (NN + 255) / 256;   // 150
    const int gE   = (EE + 255) / 256;
    const int gBM  = (NN + 63) / 64;     // 599  (k_gemm128 M-tiles)
    const int g544 = (NN + 31) / 32;     // 1198 (k_gemm544, BM=32)
    const int gR   = (NN + 7) / 8;       // k_row: 8 rows per 256-thr block

    // --- weight splits ---
    k_bsplit<<<(FF * CC + 255) / 256, 256, 0, stream>>>(W_in, bt_in_h, bt_in_l, FF);
    for (int l = 0; l < LL; l++)
        k_bsplit<<<(CC * CC + 255) / 256, 256, 0, stream>>>(
            W_gcn + (size_t)l * CC * CC,
            bt_gcn_h + (size_t)l * CC * CC, bt_gcn_l + (size_t)l * CC * CC, CC);

    // --- graph preprocessing: CSR by dst + symmetric norm ---
    k_prep<<<gN, 256, 0, stream>>>(feature, emb, val, deg, fill, NN);
    k_deg<<<gE, 256, 0, stream>>>(e_dst, deg, EE);
    k_dinv<<<gN, 256, 0, stream>>>(deg, dinv, NN);
    k_scan1<<<gN, 256, 0, stream>>>(deg, part, NN);
    k_scan2<<<1, 256, 0, stream>>>(part, part_ex, gN);
    k_scan3<<<gN, 256, 0, stream>>>(deg, part_ex, rowptr, NN);
    k_fill<<<gE, 256, 0, stream>>>(e_src, e_dst, dinv, rowptr, fill,
                                   csr_src, csr_w, EE);

    // --- input layer: BM=32 one-shot GEMM, A bf16-hi, 4 blocks/CU ---
    k_gemm544<true><<<g544, 256, 0, stream>>>(feature, val,
                                              bt_in_h, bt_in_l, bufHb, NN);
    k_row<0><<<gR, 256, 0, stream>>>(bufHb, rowptr, csr_src, csr_w, dinv, b_in,
                                     Xh, nullptr, nullptr, NN);

    // --- 4 GcnUnits (last one fuses the W_out dot -> gpre) ---
    for (int l = 0; l < LL - 1; l++) {
        k_gemm128<<<dim3(gBM, 2), 256, 0, stream>>>(Xh,
            bt_gcn_h + (size_t)l * CC * CC, bt_gcn_l + (size_t)l * CC * CC,
            bufHb, NN);
        k_row<1><<<gR, 256, 0, stream>>>(bufHb, rowptr, csr_src, csr_w, dinv,
                                         b_gcn + (size_t)l * CC, Xh,
                                         nullptr, nullptr, NN);
    }
    k_gemm128<<<dim3(gBM, 2), 256, 0, stream>>>(Xh,
        bt_gcn_h + (size_t)(LL - 1) * CC * CC,
        bt_gcn_l + (size_t)(LL - 1) * CC * CC, bufHb, NN);
    k_row<2><<<gR, 256, 0, stream>>>(bufHb, rowptr, csr_src, csr_w, dinv,
                                     b_gcn + (size_t)(LL - 1) * CC,
                                     nullptr, W_out, gpre, NN);

    // --- output conv epilogue (C=1 gather) ---
    k_row1<<<gN, 256, 0, stream>>>(gpre, rowptr, csr_src, csr_w, dinv, b_out,
                                   g, NN);

    // --- FC head ---
    k_hacc_init<<<1, 128, 0, stream>>>(b_fc1, hacc);
    k_fc1<<<512, 256, 0, stream>>>(g, W_fc1, hacc, NN);
    k_fc2<<<(PP + 255) / 256, 256, 0, stream>>>(hacc, W_fc2, b_fc2, out, PP);
}

// Round 16
// 522.665 us; speedup vs baseline: 1.3174x; 1.0368x over previous
//
#include <hip/hip_runtime.h>

// Problem constants (from reference)
#define NN 38332          // nodes
#define FF 544            // input features
#define CC 128            // channels
#define LL 4              // gcn layers
#define EE (NN*16)        // edges (613312)
#define PP 38333          // POI_LEN (output size)

typedef __attribute__((ext_vector_type(8))) short short8v;
typedef __attribute__((ext_vector_type(4))) float floatx4;

static __device__ __forceinline__ float lrelu(float x) {
    return x >= 0.f ? x : 0.01f * x;
}

// fp32 -> bf16 round-to-nearest-even (bit trick)
static __device__ __forceinline__ short f2bf(float f) {
    unsigned u = __float_as_uint(f);
    unsigned r = (u + 0x7fffu + ((u >> 16) & 1u)) >> 16;
    return (short)r;
}
static __device__ __forceinline__ float bf2f(short s) {
    return __uint_as_float(((unsigned)(unsigned short)s) << 16);
}

// async global->LDS, 16B per lane. ldst must be WAVE-UNIFORM base; HW writes
// lane i's 16B at ldst + i*16 (m97/m104 semantics).
static __device__ __forceinline__ void async_ld16(const void* gsrc, void* ldst) {
    __builtin_amdgcn_global_load_lds(
        (const __attribute__((address_space(1))) unsigned int*)gsrc,
        (__attribute__((address_space(3))) unsigned int*)ldst,
        16, 0, 0);
}

// ---------------------------------------------------------------------------
// Prep: val[i] = emb[poi[i/128]*128 + i%128]; deg init 1 (self loop); fill=0
// ---------------------------------------------------------------------------
__global__ __launch_bounds__(256) void k_prep(const float* __restrict__ feature,
                                              const float* __restrict__ emb,
                                              float* __restrict__ val,
                                              float* __restrict__ deg,
                                              int* __restrict__ fill, int n) {
    int i = blockIdx.x * 256 + threadIdx.x;
    if (i >= n) return;
    int row = i >> 7;
    int ch  = i & 127;
    int id  = (int)feature[row * FF];
    val[i]  = emb[id * CC + ch];
    deg[i]  = 1.0f;
    fill[i] = 0;
}

__global__ __launch_bounds__(256) void k_deg(const int* __restrict__ dst,
                                             float* __restrict__ deg, int e) {
    int i = blockIdx.x * 256 + threadIdx.x;
    if (i >= e) return;
    atomicAdd(&deg[dst[i]], 1.0f);
}

__global__ __launch_bounds__(256) void k_dinv(const float* __restrict__ deg,
                                              float* __restrict__ dinv, int n) {
    int i = blockIdx.x * 256 + threadIdx.x;
    if (i >= n) return;
    dinv[i] = rsqrtf(deg[i]);
}

// ---------------------------------------------------------------------------
// Parallel 3-pass exclusive scan of (deg-1) -> rowptr
// ---------------------------------------------------------------------------
__global__ __launch_bounds__(256) void k_scan1(const float* __restrict__ deg,
                                               int* __restrict__ partial, int n) {
    __shared__ int s[256];
    int i = blockIdx.x * 256 + threadIdx.x;
    int t = threadIdx.x;
    s[t] = (i < n) ? (int)deg[i] - 1 : 0;
    __syncthreads();
    #pragma unroll
    for (int off = 128; off > 0; off >>= 1) {
        if (t < off) s[t] += s[t + off];
        __syncthreads();
    }
    if (t == 0) partial[blockIdx.x] = s[0];
}

__global__ __launch_bounds__(256) void k_scan2(const int* __restrict__ partial,
                                               int* __restrict__ partial_ex, int nb) {
    __shared__ int s[256];
    int t = threadIdx.x;
    s[t] = (t < nb) ? partial[t] : 0;
    __syncthreads();
    #pragma unroll
    for (int off = 1; off < 256; off <<= 1) {
        int v = (t >= off) ? s[t - off] : 0;
        __syncthreads();
        s[t] += v;
        __syncthreads();
    }
    partial_ex[t] = (t == 0) ? 0 : s[t - 1];
}

__global__ __launch_bounds__(256) void k_scan3(const float* __restrict__ deg,
                                               const int* __restrict__ partial_ex,
                                               int* __restrict__ rowptr, int n) {
    __shared__ int s[256];
    int i = blockIdx.x * 256 + threadIdx.x;
    int t = threadIdx.x;
    int d = (i < n) ? (int)deg[i] - 1 : 0;
    s[t] = d;
    __syncthreads();
    #pragma unroll
    for (int off = 1; off < 256; off <<= 1) {
        int v = (t >= off) ? s[t - off] : 0;
        __syncthreads();
        s[t] += v;
        __syncthreads();
    }
    int incl = s[t];
    int base = partial_ex[blockIdx.x];
    if (i < n) rowptr[i] = base + incl - d;
    if (i == n - 1) rowptr[n] = base + incl;
}

__global__ __launch_bounds__(256) void k_fill(const int* __restrict__ src,
                                              const int* __restrict__ dst,
                                              const float* __restrict__ dinv,
                                              const int* __restrict__ rowptr,
                                              int* __restrict__ fill,
                                              int* __restrict__ csr_src,
                                              float* __restrict__ csr_w, int e) {
    int i = blockIdx.x * 256 + threadIdx.x;
    if (i >= e) return;
    int d = dst[i], s = src[i];
    int pos = rowptr[d] + atomicAdd(&fill[d], 1);
    csr_src[pos] = s;
    csr_w[pos]   = dinv[s] * dinv[d];
}

// ---------------------------------------------------------------------------
// B precompute: W[K][128] fp32 -> Bt[128][K] bf16 (transposed, hi only —
// r16: absmax frozen at 2^-9 through A/H/X bf16 drops; lo-half is below
// the error floor).
// ---------------------------------------------------------------------------
__global__ __launch_bounds__(256) void k_bsplit(const float* __restrict__ W,
                                                short* __restrict__ Bth, int K) {
    int idx = blockIdx.x * 256 + threadIdx.x;
    if (idx >= K * 128) return;
    int bn = idx / K, k = idx - bn * K;
    Bth[idx] = f2bf(W[k * CC + bn]);
}

// ---------------------------------------------------------------------------
// Input GEMM (K=544), BM=32, one-shot staging, pipelined B (hi only):
// 2 MFMA/kit/mt, B stream halved. LDS 34.8KB. H store bf16.
// ---------------------------------------------------------------------------
template <bool SUBST>
__global__ __launch_bounds__(256, 2) void k_gemm544(const float* __restrict__ A,
                                                    const float* __restrict__ val,
                                                    const short* __restrict__ Bth,
                                                    short* __restrict__ Hb, int n) {
    __shared__ __align__(16) short Ah_s[68 * 256];   // 34.8 KB (hi only)

    const int t  = threadIdx.x;
    const int i0 = blockIdx.x * 32;

    // --- Phase 1: stage A hi (17 independent float4 loads/thread) ---
    {
        const int srow = t >> 3;             // 0..31 (local row)
        const int c4p  = t & 7;              // float4 column phase
        int rg = i0 + srow;
        if (rg > n - 1) rg = n - 1;          // clamp pad rows (never stored)
        const float* ap = A + (size_t)rg * FF;
        #pragma unroll
        for (int j = 0; j < 17; j++) {
            int col4 = c4p + 8 * j;          // 0..135
            float4 v = *(const float4*)(ap + col4 * 4);
            if (SUBST && col4 == 0) v.x = val[rg];
            short4 hv;
            hv.x = f2bf(v.x); hv.y = f2bf(v.y);
            hv.z = f2bf(v.z); hv.w = f2bf(v.w);
            int c0   = col4 * 4;             // float column 0..543
            int kit  = c0 >> 5;
            int sel4 = (c0 >> 3) & 3;
            int pos  = c0 & 7;               // 0 or 4
            int off  = (kit * 4 + sel4) * 256 + srow * 8 + pos;
            *(short4*)&Ah_s[off] = hv;
        }
    }

    const int lane = t & 63;
    const int w    = t >> 6;
    const int fr   = lane & 15;
    const int sel  = lane >> 4;

    const short* gb0h = Bth + (size_t)((w * 2 + 0) * 16 + fr) * FF;
    const short* gb1h = Bth + (size_t)((w * 2 + 1) * 16 + fr) * FF;
    const int so = sel * 8;

    // hoist kit 0 and kit 1 B loads above the barrier (hide under the wait)
    short8v p0b0h = *(const short8v*)(gb0h + so);
    short8v p0b1h = *(const short8v*)(gb1h + so);
    short8v p1b0h = *(const short8v*)(gb0h + 32 + so);
    short8v p1b1h = *(const short8v*)(gb1h + 32 + so);

    __syncthreads();                          // the ONLY barrier

    floatx4 acc[2][2];
    #pragma unroll
    for (int mt = 0; mt < 2; mt++)
        #pragma unroll
        for (int nt = 0; nt < 2; nt++)
            acc[mt][nt] = (floatx4){0.f, 0.f, 0.f, 0.f};

    #pragma unroll
    for (int kit = 0; kit < 17; kit++) {
        short8v b0h, b1h;
        if (kit == 0) {
            b0h = p0b0h; b1h = p0b1h;
        } else if (kit == 1) {
            b0h = p1b0h; b1h = p1b1h;
        } else {
            const int ko = kit * 32 + so;
            b0h = *(const short8v*)(gb0h + ko);
            b1h = *(const short8v*)(gb1h + ko);
        }
        short8v ah[2];
        #pragma unroll
        for (int mt = 0; mt < 2; mt++) {
            int offA = (kit * 4 + sel) * 256 + (mt * 16 + fr) * 8;
            ah[mt] = *(const short8v*)&Ah_s[offA];
        }
        #pragma unroll
        for (int mt = 0; mt < 2; mt++) {
            acc[mt][0] = __builtin_amdgcn_mfma_f32_16x16x32_bf16(ah[mt], b0h, acc[mt][0], 0, 0, 0);
            acc[mt][1] = __builtin_amdgcn_mfma_f32_16x16x32_bf16(ah[mt], b1h, acc[mt][1], 0, 0, 0);
        }
    }

    #pragma unroll
    for (int mt = 0; mt < 2; mt++)
        #pragma unroll
        for (int nt = 0; nt < 2; nt++) {
            int col = (w * 2 + nt) * 16 + fr;
            #pragma unroll
            for (int r = 0; r < 4; r++) {
                int row = i0 + mt * 16 + sel * 4 + r;
                if (row < n) Hb[(size_t)row * CC + col] = f2bf(acc[mt][nt][r]);
            }
        }
}

// ---------------------------------------------------------------------------
// C-GEMM (K=128), N-SPLIT x2, X bf16-hi, B bf16-hi: 1 MFMA/kit/mt (16 total
// per wave), B L2 stream halved. Hb store bf16.
// ---------------------------------------------------------------------------
__global__ __launch_bounds__(256) void k_gemm128(const short* __restrict__ Xh,
                                                 const short* __restrict__ Bth,
                                                 short* __restrict__ Hb, int n) {
    __shared__ __align__(16) short Ah_s[16 * 512];   // 16 KB
    const int t    = threadIdx.x;
    const int w    = t >> 6;
    const int lane = t & 63;
    const int fr   = lane & 15;
    const int sel  = lane >> 4;
    const int i0   = blockIdx.x * 64;
    const int nh   = blockIdx.y;             // N-half: cols nh*64 ..

    // --- B fragments -> registers (1 n-tile per wave) ---
    short8v bh[4];
    {
        int nidx = (nh * 4 + w) * 16 + fr;
        #pragma unroll
        for (int kit = 0; kit < 4; kit++)
            bh[kit] = *(const short8v*)&Bth[nidx * 128 + kit * 32 + sel * 8];
    }

    floatx4 acc[4];
    #pragma unroll
    for (int mt = 0; mt < 4; mt++) acc[mt] = (floatx4){0.f, 0.f, 0.f, 0.f};

    int rA = i0 + lane;
    if (rA > n - 1) rA = n - 1;              // clamp pad rows (never stored)
    const short* gh = Xh + (size_t)rA * 128 + w * 8;

    #pragma unroll
    for (int kit = 0; kit < 4; kit++)
        async_ld16(gh + kit * 32, &Ah_s[(kit * 4 + w) * 512]);
    __syncthreads();                          // single drain for all staging

    #pragma unroll
    for (int kit = 0; kit < 4; kit++) {
        short8v ah[4];
        #pragma unroll
        for (int mt = 0; mt < 4; mt++) {
            int off = (kit * 4 + sel) * 512 + (mt * 16 + fr) * 8;
            ah[mt] = *(const short8v*)&Ah_s[off];
        }
        #pragma unroll
        for (int mt = 0; mt < 4; mt++)
            acc[mt] = __builtin_amdgcn_mfma_f32_16x16x32_bf16(ah[mt], bh[kit], acc[mt], 0, 0, 0);
    }

    {
        int col = (nh * 4 + w) * 16 + fr;
        #pragma unroll
        for (int mt = 0; mt < 4; mt++) {
            #pragma unroll
            for (int r = 0; r < 4; r++) {
                int row = i0 + mt * 16 + sel * 4 + r;
                if (row < n) Hb[(size_t)row * CC + col] = f2bf(acc[mt][r]);
            }
        }
    }
}

// ---------------------------------------------------------------------------
// Row gather v8: one row per 32-lane half, 8 rows/block, bf16 Hb gather,
// X written as bf16-hi only.
// MODE 0: x=lrelu(t); MODE 1: x=lrelu(t)+t; MODE 2: MODE1 + fused W_out dot.
// ---------------------------------------------------------------------------
template <int MODE>
__global__ __launch_bounds__(256) void k_row(const short* __restrict__ Hb,
                                             const int* __restrict__ rowptr,
                                             const int* __restrict__ csr_src,
                                             const float* __restrict__ csr_w,
                                             const float* __restrict__ dinv,
                                             const float* __restrict__ bias,
                                             short* __restrict__ Xh,
                                             const float* __restrict__ Wout,
                                             float* __restrict__ gpre, int n) {
    const int w    = threadIdx.x >> 6;
    const int l    = threadIdx.x & 63;
    const int half = l >> 5;
    const int cl   = l & 31;                 // channels 4cl..4cl+3
    const int row  = blockIdx.x * 8 + w * 2 + half;
    const bool ok  = (row < n);
    const short4* Hb4 = (const short4*)Hb;   // [N][32] short4
    float a0 = 0.f, a1 = 0.f, a2 = 0.f, a3 = 0.f;
    int rs = 0, re = 0;
    if (ok) {
        const float di = dinv[row];
        const float dd = di * di;
        float4 b4 = ((const float4*)bias)[cl];
        short4 s4 = Hb4[(size_t)row * 32 + cl];
        a0 = b4.x + bf2f(s4.x) * dd; a1 = b4.y + bf2f(s4.y) * dd;
        a2 = b4.z + bf2f(s4.z) * dd; a3 = b4.w + bf2f(s4.w) * dd;
        rs = rowptr[row]; re = rowptr[row + 1];
    }
    for (int base = rs; base < re; base += 32) {
        int m = re - base; if (m > 32) m = 32;
        int myi = 0; float myw = 0.f;
        if (cl < m) { myi = csr_src[base + cl]; myw = csr_w[base + cl]; }
        const int lb = half * 32;            // this half's lane base
        int j = 0;
        for (; j + 4 <= m; j += 4) {
            int   i0 = __shfl(myi, lb + j, 64),     i1 = __shfl(myi, lb + j + 1, 64);
            int   i2 = __shfl(myi, lb + j + 2, 64), i3 = __shfl(myi, lb + j + 3, 64);
            float w0 = __shfl(myw, lb + j, 64),     w1 = __shfl(myw, lb + j + 1, 64);
            float w2 = __shfl(myw, lb + j + 2, 64), w3 = __shfl(myw, lb + j + 3, 64);
            short4 h0 = Hb4[(size_t)i0 * 32 + cl];
            short4 h1 = Hb4[(size_t)i1 * 32 + cl];
            short4 h2 = Hb4[(size_t)i2 * 32 + cl];
            short4 h3 = Hb4[(size_t)i3 * 32 + cl];
            a0 += bf2f(h0.x) * w0; a1 += bf2f(h0.y) * w0; a2 += bf2f(h0.z) * w0; a3 += bf2f(h0.w) * w0;
            a0 += bf2f(h1.x) * w1; a1 += bf2f(h1.y) * w1; a2 += bf2f(h1.z) * w1; a3 += bf2f(h1.w) * w1;
            a0 += bf2f(h2.x) * w2; a1 += bf2f(h2.y) * w2; a2 += bf2f(h2.z) * w2; a3 += bf2f(h2.w) * w2;
            a0 += bf2f(h3.x) * w3; a1 += bf2f(h3.y) * w3; a2 += bf2f(h3.z) * w3; a3 += bf2f(h3.w) * w3;
        }
        for (; j < m; j++) {
            int   idx = __shfl(myi, lb + j, 64);
            float wv  = __shfl(myw, lb + j, 64);
            short4 hv = Hb4[(size_t)idx * 32 + cl];
            a0 += bf2f(hv.x) * wv; a1 += bf2f(hv.y) * wv;
            a2 += bf2f(hv.z) * wv; a3 += bf2f(hv.w) * wv;
        }
    }
    if (!ok) return;
    float r0 = lrelu(a0), r1 = lrelu(a1), r2 = lrelu(a2), r3 = lrelu(a3);
    float x0 = MODE ? (r0 + a0) : r0;
    float x1 = MODE ? (r1 + a1) : r1;
    float x2 = MODE ? (r2 + a2) : r2;
    float x3 = MODE ? (r3 + a3) : r3;
    if (MODE == 2) {
        float4 w4 = ((const float4*)Wout)[cl];
        float p = x0 * w4.x + x1 * w4.y + x2 * w4.z + x3 * w4.w;
        #pragma unroll
        for (int off = 16; off > 0; off >>= 1) p += __shfl_down(p, off, 32);
        if (cl == 0) gpre[row] = p;
    } else {
        short4 hi4 = make_short4(f2bf(x0), f2bf(x1), f2bf(x2), f2bf(x3));
        size_t o = (size_t)row * 128 + cl * 4;
        *(short4*)&Xh[o] = hi4;
    }
}

__global__ __launch_bounds__(256) void k_row1(const float* __restrict__ gpre,
                                              const int* __restrict__ rowptr,
                                              const int* __restrict__ csr_src,
                                              const float* __restrict__ csr_w,
                                              const float* __restrict__ dinv,
                                              const float* __restrict__ bout,
                                              float* __restrict__ g, int n) {
    int i = blockIdx.x * 256 + threadIdx.x;
    if (i >= n) return;
    float di = dinv[i];
    float acc = bout[0] + gpre[i] * di * di;
    int e1 = rowptr[i + 1];
    for (int e = rowptr[i]; e < e1; e++)
        acc += gpre[csr_src[e]] * csr_w[e];
    g[i] = lrelu(acc);
}

__global__ void k_hacc_init(const float* __restrict__ bfc1, float* __restrict__ hacc) {
    hacc[threadIdx.x] = bfc1[threadIdx.x];
}

// g[N] @ W_fc1[N,128] : 512 blocks x 256 thr (2 row streams), LDS reduce
__global__ __launch_bounds__(256) void k_fc1(const float* __restrict__ g,
                                             const float* __restrict__ Wfc1,
                                             float* __restrict__ hacc, int n) {
    __shared__ float red[256];
    int c = threadIdx.x & 127;
    int p = threadIdx.x >> 7;
    int nb = gridDim.x;
    int chunk = (n + nb - 1) / nb;
    int s = blockIdx.x * chunk;
    int e = min(n, s + chunk);
    float acc = 0.f;
    for (int i = s + p; i < e; i += 2)
        acc += g[i] * Wfc1[(size_t)i * CC + c];
    red[threadIdx.x] = acc;
    __syncthreads();
    if (p == 0) atomicAdd(&hacc[c], red[c] + red[128 + c]);
}

__global__ __launch_bounds__(256) void k_fc2(const float* __restrict__ hacc,
                                             const float* __restrict__ Wfc2,
                                             const float* __restrict__ bfc2,
                                             float* __restrict__ out, int P) {
    __shared__ float sh[128];
    int t = threadIdx.x;
    if (t < 128) { float v = hacc[t]; sh[t] = v > 0.f ? v : 0.f; }
    __syncthreads();
    int k = blockIdx.x * 256 + t;
    if (k >= P) return;
    float acc = bfc2[k];
    #pragma unroll 8
    for (int j = 0; j < 128; j++)
        acc += sh[j] * Wfc2[(size_t)j * P + k];
    out[k] = acc > 0.f ? acc : 0.f;
}

// ---------------------------------------------------------------------------
extern "C" void kernel_launch(void* const* d_in, const int* in_sizes, int n_in,
                              void* d_out, int out_size, void* d_ws, size_t ws_size,
                              hipStream_t stream) {
    const float* feature = (const float*)d_in[0];
    const int*   eidx  = (const int*)d_in[2];
    const int*   e_src = eidx;
    const int*   e_dst = eidx + EE;
    const float* emb   = (const float*)d_in[3];
    const float* W_in  = (const float*)d_in[4];
    const float* b_in  = (const float*)d_in[5];
    const float* W_gcn = (const float*)d_in[6];
    const float* b_gcn = (const float*)d_in[7];
    const float* W_out = (const float*)d_in[8];
    const float* b_out = (const float*)d_in[9];
    const float* W_fc1 = (const float*)d_in[10];
    const float* b_fc1 = (const float*)d_in[11];
    const float* W_fc2 = (const float*)d_in[12];
    const float* b_fc2 = (const float*)d_in[13];
    float* out = (float*)d_out;

    float* w = (float*)d_ws;
    size_t off = 0;
    auto take = [&](size_t elems) -> float* {
        float* p = w + off;
        off += (elems + 63) & ~(size_t)63;
        return p;
    };
    float* val     = take(NN);
    float* deg     = take(NN);
    float* dinv    = take(NN);
    int*   rowptr  = (int*)take(NN + 1);
    int*   fill    = (int*)take(NN);
    int*   csr_src = (int*)take(EE);
    float* csr_w   = take(EE);
    short* bufHb   = (short*)take((size_t)NN * CC / 2); // H (bf16 hi)
    short* Xh      = (short*)take((size_t)NN * CC / 2); // X (bf16 hi only)
    float* gpre    = take(NN);
    float* g       = take(NN);
    float* hacc    = take(128);
    short* bt_in_h  = (short*)take(FF * CC / 2);
    short* bt_gcn_h = (short*)take((size_t)LL * CC * CC / 2);
    int*   part     = (int*)take(256);
    int*   part_ex  = (int*)take(256);
    (void)ws_size; (void)in_sizes; (void)n_in; (void)out_size;

    const int gN   = (NN + 255) / 256;   // 150
    const int gE   = (EE + 255) / 256;
    const int gBM  = (NN + 63) / 64;     // 599  (k_gemm128 M-tiles)
    const int g544 = (NN + 31) / 32;     // 1198 (k_gemm544, BM=32)
    const int gR   = (NN + 7) / 8;       // k_row: 8 rows per 256-thr block

    // --- weight transposes (bf16 hi only) ---
    k_bsplit<<<(FF * CC + 255) / 256, 256, 0, stream>>>(W_in, bt_in_h, FF);
    for (int l = 0; l < LL; l++)
        k_bsplit<<<(CC * CC + 255) / 256, 256, 0, stream>>>(
            W_gcn + (size_t)l * CC * CC,
            bt_gcn_h + (size_t)l * CC * CC, CC);

    // --- graph preprocessing: CSR by dst + symmetric norm ---
    k_prep<<<gN, 256, 0, stream>>>(feature, emb, val, deg, fill, NN);
    k_deg<<<gE, 256, 0, stream>>>(e_dst, deg, EE);
    k_dinv<<<gN, 256, 0, stream>>>(deg, dinv, NN);
    k_scan1<<<gN, 256, 0, stream>>>(deg, part, NN);
    k_scan2<<<1, 256, 0, stream>>>(part, part_ex, gN);
    k_scan3<<<gN, 256, 0, stream>>>(deg, part_ex, rowptr, NN);
    k_fill<<<gE, 256, 0, stream>>>(e_src, e_dst, dinv, rowptr, fill,
                                   csr_src, csr_w, EE);

    // --- input layer ---
    k_gemm544<true><<<g544, 256, 0, stream>>>(feature, val, bt_in_h, bufHb, NN);
    k_row<0><<<gR, 256, 0, stream>>>(bufHb, rowptr, csr_src, csr_w, dinv, b_in,
                                     Xh, nullptr, nullptr, NN);

    // --- 4 GcnUnits (last one fuses the W_out dot -> gpre) ---
    for (int l = 0; l < LL - 1; l++) {
        k_gemm128<<<dim3(gBM, 2), 256, 0, stream>>>(Xh,
            bt_gcn_h + (size_t)l * CC * CC, bufHb, NN);
        k_row<1><<<gR, 256, 0, stream>>>(bufHb, rowptr, csr_src, csr_w, dinv,
                                         b_gcn + (size_t)l * CC, Xh,
                                         nullptr, nullptr, NN);
    }
    k_gemm128<<<dim3(gBM, 2), 256, 0, stream>>>(Xh,
        bt_gcn_h + (size_t)(LL - 1) * CC * CC, bufHb, NN);
    k_row<2><<<gR, 256, 0, stream>>>(bufHb, rowptr, csr_src, csr_w, dinv,
                                     b_gcn + (size_t)(LL - 1) * CC,
                                     nullptr, W_out, gpre, NN);

    // --- output conv epilogue (C=1 gather) ---
    k_row1<<<gN, 256, 0, stream>>>(gpre, rowptr, csr_src, csr_w, dinv, b_out,
                                   g, NN);

    // --- FC head ---
    k_hacc_init<<<1, 128, 0, stream>>>(b_fc1, hacc);
    k_fc1<<<512, 256, 0, stream>>>(g, W_fc1, hacc, NN);
    k_fc2<<<(PP + 255) / 256, 256, 0, stream>>>(hacc, W_fc2, b_fc2, out, PP);
}